// Round 1
// baseline (6608.521 us; speedup 1.0000x reference)
//
#include <hip/hip_runtime.h>
#include <cmath>

#define B_ 4
#define S_ 1024
#define H_ 1024

// ---------------------------------------------------------------- gating ----
// one wave per token: logits = x_row @ Wg[1024,4]; top-2 -> softmax -> dense
// per-expert weights gw[token][4] (0 for unselected experts).
__global__ __launch_bounds__(64) void gate_kernel(
    const float* __restrict__ x, const float* __restrict__ Wg,
    float* __restrict__ gw) {
  int t = blockIdx.x;      // token 0..4095
  int lane = threadIdx.x;  // 0..63
  const float* xr = x + (size_t)t * H_;
  float a0 = 0.f, a1 = 0.f, a2 = 0.f, a3 = 0.f;
  for (int h = lane; h < H_; h += 64) {
    float xv = xr[h];
    const float* wr = Wg + h * 4;
    a0 += xv * wr[0]; a1 += xv * wr[1]; a2 += xv * wr[2]; a3 += xv * wr[3];
  }
  for (int off = 32; off > 0; off >>= 1) {
    a0 += __shfl_down(a0, off);
    a1 += __shfl_down(a1, off);
    a2 += __shfl_down(a2, off);
    a3 += __shfl_down(a3, off);
  }
  if (lane == 0) {
    float v[4] = {a0, a1, a2, a3};
    int i0 = 0; float b0 = v[0];
    for (int e = 1; e < 4; ++e) if (v[e] > b0) { b0 = v[e]; i0 = e; }   // first max (jax tie rule)
    int i1 = -1; float b1 = -INFINITY;
    for (int e = 0; e < 4; ++e) { if (e == i0) continue; if (v[e] > b1) { b1 = v[e]; i1 = e; } }
    float e1v = expf(b1 - b0);
    float w0 = 1.f / (1.f + e1v);
    float w1 = e1v / (1.f + e1v);
    float o[4] = {0.f, 0.f, 0.f, 0.f};
    o[i0] = w0; o[i1] = w1;
    float* g = gw + t * 4;
    g[0] = o[0]; g[1] = o[1]; g[2] = o[2]; g[3] = o[3];
  }
}

// ------------------------------------------------------------------ GEMM ----
// C[M,N] = A[M,K] @ W[K,N] + bias ; 64x64 tile, BK=16, 256 thr, 4x4/thread.
// mode 0: C = val (proj; optional elu+1 for linear-attn q/k)
// mode 1: C = gw[m][expert] * val   (first expert's output projection)
// mode 2: C += gw[m][expert] * val  (remaining experts)
#define BM 64
#define BN 64
#define BK 16
__global__ __launch_bounds__(256) void gemm_kernel(
    const float* __restrict__ A, const float* __restrict__ W,
    const float* __restrict__ bias, float* __restrict__ C,
    int M, int N, int K, int lda,
    int mode, int do_elu, const float* __restrict__ gw, int expert) {
  __shared__ float As[BK][BM + 1];
  __shared__ float Bs[BK][BN + 1];
  int tid = threadIdx.x;
  int m0 = blockIdx.y * BM, n0 = blockIdx.x * BN;
  int tx = tid % 16, ty = tid / 16;
  int arow = tid / 16, acol = tid % 16;  // A-load: 16 rows x 16 k, x4 rows
  int brow = tid / 64, bcol = tid % 64;  // B-load: 4 k x 64 n, x4 k
  float acc[4][4] = {};
  for (int k0 = 0; k0 < K; k0 += BK) {
#pragma unroll
    for (int i = 0; i < 4; ++i) {
      int m = m0 + arow + i * 16;
      int kk = k0 + acol;
      As[acol][arow + i * 16] = (kk < K) ? A[(size_t)m * lda + kk] : 0.f;
    }
#pragma unroll
    for (int i = 0; i < 4; ++i) {
      int kk = k0 + brow + i * 4;
      int n = n0 + bcol;
      Bs[brow + i * 4][bcol] = (kk < K && n < N) ? W[(size_t)kk * N + n] : 0.f;
    }
    __syncthreads();
#pragma unroll
    for (int kk = 0; kk < BK; ++kk) {
      float a[4], b[4];
#pragma unroll
      for (int i = 0; i < 4; ++i) a[i] = As[kk][ty * 4 + i];
#pragma unroll
      for (int j = 0; j < 4; ++j) b[j] = Bs[kk][tx * 4 + j];
#pragma unroll
      for (int i = 0; i < 4; ++i)
#pragma unroll
        for (int j = 0; j < 4; ++j) acc[i][j] += a[i] * b[j];
    }
    __syncthreads();
  }
#pragma unroll
  for (int i = 0; i < 4; ++i) {
    int m = m0 + ty * 4 + i;
#pragma unroll
    for (int j = 0; j < 4; ++j) {
      int n = n0 + tx * 4 + j;
      if (n >= N) continue;
      float val = acc[i][j] + bias[n];
      if (do_elu) val = (val > 0.f) ? val + 1.f : expf(val);  // elu(x)+1
      size_t ci = (size_t)m * N + n;
      if (mode == 0) {
        C[ci] = val;
      } else {
        float g = gw[m * 4 + expert];
        if (mode == 1) C[ci] = g * val;
        else           C[ci] += g * val;
      }
    }
  }
}

// ----------------------------------------------- std / local attention ------
// flash-style: per block (b, h, 32-query tile), loop 32-key tiles with
// online softmax. HD template (128 or 85). w2 = half window (1<<20 = none).
template <int HD>
__global__ __launch_bounds__(256) void attn_kernel(
    const float* __restrict__ q, const float* __restrict__ k,
    const float* __restrict__ v, const int* __restrict__ amask,
    float* __restrict__ ao, int pd, int w2) {
  constexpr int QT = 32, KT = 32;
  constexpr int NCOL = (HD + 7) / 8;
  constexpr int PHD = NCOL * 8;
  __shared__ float Qs[QT][PHD + 1];
  __shared__ float Ks[KT][PHD + 1];
  __shared__ float Vs[KT][PHD + 1];
  __shared__ float Ss[QT][KT + 1];
  __shared__ float mrow[QT], lrow[QT], alph[QT];
  int tid = threadIdx.x;
  int q0 = blockIdx.x * QT;
  int h = blockIdx.y;
  int b = blockIdx.z;
  const float scale = rsqrtf((float)HD);
  size_t base = ((size_t)b * S_) * pd + (size_t)h * HD;

  for (int idx = tid; idx < QT * PHD; idx += 256) {
    int r = idx / PHD, d = idx % PHD;
    Qs[r][d] = (d < HD) ? q[base + (size_t)(q0 + r) * pd + d] : 0.f;
  }
  if (tid < QT) { mrow[tid] = -INFINITY; lrow[tid] = 0.f; }
  float acc[NCOL];
#pragma unroll
  for (int c = 0; c < NCOL; ++c) acc[c] = 0.f;
  int r = tid % 32, grp = tid / 32;
  __syncthreads();

  for (int j0 = 0; j0 < S_; j0 += KT) {
    if (j0 > q0 + QT - 1 + w2) break;       // uniform: past window
    if (j0 + KT - 1 < q0 - w2) continue;    // uniform: before window
    for (int idx = tid; idx < KT * PHD; idx += 256) {
      int rr = idx / PHD, d = idx % PHD;
      size_t g = base + (size_t)(j0 + rr) * pd + d;
      float kv_ = 0.f, vv_ = 0.f;
      if (d < HD) { kv_ = k[g]; vv_ = v[g]; }
      Ks[rr][d] = kv_;
      Vs[rr][d] = vv_;
    }
    __syncthreads();
    {  // scores: each thread 4 (qi,kj) dots, qv hoisted (5 LDS reads / 4 fma)
      int qi = tid % 32;
      int kjb = (tid / 32) * 4;
      float s0 = 0.f, s1 = 0.f, s2 = 0.f, s3 = 0.f;
      for (int d = 0; d < HD; ++d) {
        float qv = Qs[qi][d];
        s0 += qv * Ks[kjb + 0][d];
        s1 += qv * Ks[kjb + 1][d];
        s2 += qv * Ks[kjb + 2][d];
        s3 += qv * Ks[kjb + 3][d];
      }
      float sv[4] = {s0, s1, s2, s3};
#pragma unroll
      for (int jj = 0; jj < 4; ++jj) {
        int kj = kjb + jj;
        int dj = (j0 + kj) - (q0 + qi);
        bool ok = (dj <= w2) && (dj >= -w2);
        if (amask[b * S_ + j0 + kj] == 0) ok = false;
        Ss[qi][kj] = ok ? sv[jj] * scale : -1e30f;
      }
    }
    __syncthreads();
    if (tid < QT) {  // online-softmax row update
      int qi = tid;
      float mold = mrow[qi];
      float mx = mold;
#pragma unroll
      for (int kj = 0; kj < KT; ++kj) mx = fmaxf(mx, Ss[qi][kj]);
      float alpha;
      if (mold <= -1e29f) alpha = (mx <= -1e29f) ? 1.f : 0.f;
      else                alpha = expf(mold - mx);
      float lsum = 0.f;
#pragma unroll
      for (int kj = 0; kj < KT; ++kj) {
        float sv = Ss[qi][kj];
        float p = (sv <= -1e29f) ? 0.f : expf(sv - mx);
        Ss[qi][kj] = p;
        lsum += p;
      }
      mrow[qi] = mx;
      lrow[qi] = lrow[qi] * alpha + lsum;
      alph[qi] = alpha;
    }
    __syncthreads();
    {  // O accumulate: thread owns (row r, NCOL cols at grp*NCOL)
      float alpha = alph[r];
#pragma unroll
      for (int c = 0; c < NCOL; ++c) acc[c] *= alpha;
      for (int kj = 0; kj < KT; ++kj) {
        float p = Ss[r][kj];
#pragma unroll
        for (int c = 0; c < NCOL; ++c) acc[c] += p * Vs[kj][grp * NCOL + c];
      }
    }
    __syncthreads();
  }
  float l = lrow[r];
  float inv = (l > 0.f) ? 1.f / l : 0.f;  // all-masked row -> 0 (nan_to_num)
#pragma unroll
  for (int c = 0; c < NCOL; ++c) {
    int d = grp * NCOL + c;
    if (d < HD) ao[base + (size_t)(q0 + r) * pd + d] = acc[c] * inv;
  }
}

// ------------------------------------------------------ linear attention ----
// kv[b,h] = sum_s k_s (x) v_s  [128x128], ksum[b,h] = sum_s k_s. One block
// per (h,b); thread owns kv row tid/2, half-row (tid%2)*64.
__global__ __launch_bounds__(256) void linkv_kernel(
    const float* __restrict__ k, const float* __restrict__ v,
    float* __restrict__ kv, float* __restrict__ ksum) {
  constexpr int HD = 128;
  int h = blockIdx.x, b = blockIdx.y;
  int tid = threadIdx.x;
  __shared__ float ks[8][HD], vs[8][HD];
  int dr = tid / 2, c0 = (tid % 2) * 64;
  float acc[64];
#pragma unroll
  for (int c = 0; c < 64; ++c) acc[c] = 0.f;
  float ksacc = 0.f;
  size_t base = ((size_t)b * S_) * 1024 + (size_t)h * HD;
  for (int s0 = 0; s0 < S_; s0 += 8) {
    for (int idx = tid; idx < 8 * HD; idx += 256) {
      int rr = idx / HD, d = idx % HD;
      size_t g = base + (size_t)(s0 + rr) * 1024 + d;
      ks[rr][d] = k[g];
      vs[rr][d] = v[g];
    }
    __syncthreads();
#pragma unroll
    for (int rr = 0; rr < 8; ++rr) {
      float kval = ks[rr][dr];
#pragma unroll
      for (int c = 0; c < 64; ++c) acc[c] += kval * vs[rr][c0 + c];
    }
    if (tid < HD) {
#pragma unroll
      for (int rr = 0; rr < 8; ++rr) ksacc += ks[rr][tid];
    }
    __syncthreads();
  }
  size_t kvbase = (size_t)(b * 8 + h) * HD * HD;
  for (int c = 0; c < 64; ++c) kv[kvbase + (size_t)dr * HD + c0 + c] = acc[c];
  if (tid < HD) ksum[(size_t)(b * 8 + h) * HD + tid] = ksacc;
}

// out = (q @ kv) / (q . ksum + 1e-6); q already elu+1 from projection.
__global__ __launch_bounds__(256) void linattn_kernel(
    const float* __restrict__ q, const float* __restrict__ kv,
    const float* __restrict__ ksum, float* __restrict__ ao) {
  constexpr int HD = 128;
  int q0 = blockIdx.x * 32;
  int h = blockIdx.y, b = blockIdx.z;
  int tid = threadIdx.x;
  __shared__ float Qs[32][HD + 1];
  __shared__ float den[32];
  size_t base = ((size_t)b * S_) * 1024 + (size_t)h * HD;
  for (int idx = tid; idx < 32 * HD; idx += 256) {
    int r = idx / HD, d = idx % HD;
    Qs[r][d] = q[base + (size_t)(q0 + r) * 1024 + d];
  }
  __syncthreads();
  int r = tid % 32, grp = tid / 32;
  const float* kvb = kv + (size_t)(b * 8 + h) * HD * HD;
  float acc[16];
#pragma unroll
  for (int c = 0; c < 16; ++c) acc[c] = 0.f;
  for (int d = 0; d < HD; ++d) {
    float qv = Qs[r][d];
    const float* kvr = kvb + (size_t)d * HD + grp * 16;
#pragma unroll
    for (int c = 0; c < 16; ++c) acc[c] += qv * kvr[c];
  }
  if (tid < 32) {
    const float* ks = ksum + (size_t)(b * 8 + h) * HD;
    float dsum = 0.f;
    for (int d = 0; d < HD; ++d) dsum += Qs[tid][d] * ks[d];
    den[tid] = dsum + 1e-6f;
  }
  __syncthreads();
  float inv = 1.f / den[r];
#pragma unroll
  for (int c = 0; c < 16; ++c)
    ao[base + (size_t)(q0 + r) * 1024 + grp * 16 + c] = acc[c] * inv;
}

// ---------------------------------------------------------------- launch ----
extern "C" void kernel_launch(void* const* d_in, const int* in_sizes, int n_in,
                              void* d_out, int out_size, void* d_ws, size_t ws_size,
                              hipStream_t stream) {
  const float* x = (const float*)d_in[0];
  const float* Wg = (const float*)d_in[1];
  const int* amask = (const int*)d_in[34];
  float* out = (float*)d_out;
  char* ws = (char*)d_ws;
  // workspace layout (80 MB total)
  float* gw   = (float*)(ws + 0);                       // 64 KB
  float* kv   = (float*)(ws + (1ull << 20));            // 2 MB
  float* ksum = (float*)(ws + (3ull << 20));            // 16 KB
  float* qb   = (float*)(ws + (16ull << 20));           // 16 MB
  float* kb   = (float*)(ws + (32ull << 20));           // 16 MB
  float* vb   = (float*)(ws + (48ull << 20));           // 16 MB
  float* ao   = (float*)(ws + (64ull << 20));           // 16 MB

  gate_kernel<<<4096, 64, 0, stream>>>(x, Wg, gw);

  const int nhs[4] = {8, 12, 8, 8};
  for (int e = 0; e < 4; ++e) {
    const float* Wq = (const float*)d_in[2 + 8 * e + 0];
    const float* bq = (const float*)d_in[2 + 8 * e + 1];
    const float* Wk = (const float*)d_in[2 + 8 * e + 2];
    const float* bk = (const float*)d_in[2 + 8 * e + 3];
    const float* Wv = (const float*)d_in[2 + 8 * e + 4];
    const float* bv = (const float*)d_in[2 + 8 * e + 5];
    const float* Wo = (const float*)d_in[2 + 8 * e + 6];
    const float* bo = (const float*)d_in[2 + 8 * e + 7];
    int nh = nhs[e];
    int hd = H_ / nh;   // 128 or 85
    int pd = nh * hd;   // 1024 or 1020
    int elu = (e == 2) ? 1 : 0;  // linear attn: phi = elu+1 on q,k

    dim3 pgrid((pd + BN - 1) / BN, (B_ * S_) / BM);
    gemm_kernel<<<pgrid, 256, 0, stream>>>(x, Wq, bq, qb, B_ * S_, pd, H_, H_, 0, elu, nullptr, 0);
    gemm_kernel<<<pgrid, 256, 0, stream>>>(x, Wk, bk, kb, B_ * S_, pd, H_, H_, 0, elu, nullptr, 0);
    gemm_kernel<<<pgrid, 256, 0, stream>>>(x, Wv, bv, vb, B_ * S_, pd, H_, H_, 0, 0,   nullptr, 0);

    if (e == 2) {
      linkv_kernel<<<dim3(8, B_), 256, 0, stream>>>(kb, vb, kv, ksum);
      linattn_kernel<<<dim3(S_ / 32, 8, B_), 256, 0, stream>>>(qb, kv, ksum, ao);
    } else {
      int w2 = (e == 3) ? 32 : (1 << 20);  // WINDOW//2 for local, "inf" else
      dim3 agrid(S_ / 32, nh, B_);
      if (hd == 128)
        attn_kernel<128><<<agrid, 256, 0, stream>>>(qb, kb, vb, amask, ao, pd, w2);
      else
        attn_kernel<85><<<agrid, 256, 0, stream>>>(qb, kb, vb, amask, ao, pd, w2);
    }

    dim3 ogrid(H_ / BN, (B_ * S_) / BM);
    gemm_kernel<<<ogrid, 256, 0, stream>>>(ao, Wo, bo, out, B_ * S_, H_, pd, pd,
                                           (e == 0) ? 1 : 2, 0, gw, e);
  }
}

// Round 2
// 3602.390 us; speedup vs baseline: 1.8345x; 1.8345x over previous
//
#include <hip/hip_runtime.h>
#include <cmath>

#define B_ 4
#define S_ 1024
#define H_ 1024

typedef short bf16x8 __attribute__((ext_vector_type(8)));
typedef float f32x4 __attribute__((ext_vector_type(4)));

__device__ __forceinline__ unsigned short f2bf(float f) {
  unsigned u = __float_as_uint(f);
  u += 0x7fff + ((u >> 16) & 1);  // RTNE
  return (unsigned short)(u >> 16);
}
__device__ __forceinline__ float bf2f(unsigned short h) {
  return __uint_as_float(((unsigned)h) << 16);
}
__device__ __forceinline__ void gld16(const void* g, void* l) {
  __builtin_amdgcn_global_load_lds(
      (const __attribute__((address_space(1))) unsigned int*)g,
      (__attribute__((address_space(3))) unsigned int*)l, 16, 0, 0);
}

// ---------------------------------------------------------------- gating ----
__global__ __launch_bounds__(64) void gate_kernel(
    const float* __restrict__ x, const float* __restrict__ Wg,
    float* __restrict__ gw) {
  int t = blockIdx.x;
  int lane = threadIdx.x;
  const float* xr = x + (size_t)t * H_;
  float a0 = 0.f, a1 = 0.f, a2 = 0.f, a3 = 0.f;
  for (int h = lane; h < H_; h += 64) {
    float xv = xr[h];
    const float* wr = Wg + h * 4;
    a0 += xv * wr[0]; a1 += xv * wr[1]; a2 += xv * wr[2]; a3 += xv * wr[3];
  }
  for (int off = 32; off > 0; off >>= 1) {
    a0 += __shfl_down(a0, off);
    a1 += __shfl_down(a1, off);
    a2 += __shfl_down(a2, off);
    a3 += __shfl_down(a3, off);
  }
  if (lane == 0) {
    float v[4] = {a0, a1, a2, a3};
    int i0 = 0; float b0 = v[0];
    for (int e = 1; e < 4; ++e) if (v[e] > b0) { b0 = v[e]; i0 = e; }
    int i1 = -1; float b1 = -INFINITY;
    for (int e = 0; e < 4; ++e) { if (e == i0) continue; if (v[e] > b1) { b1 = v[e]; i1 = e; } }
    float e1v = expf(b1 - b0);
    float w0 = 1.f / (1.f + e1v);
    float w1 = e1v / (1.f + e1v);
    float o[4] = {0.f, 0.f, 0.f, 0.f};
    o[i0] = w0; o[i1] = w1;
    float* g = gw + t * 4;
    g[0] = o[0]; g[1] = o[1]; g[2] = o[2]; g[3] = o[3];
  }
}

// -------------------------------------------------------- fp32 -> bf16 ------
// dst[m][0..1023] = bf16(src[m][c]) for c < nsrc else 0.  grid: M*1024/256
__global__ __launch_bounds__(256) void conv_kernel(
    const float* __restrict__ src, unsigned short* __restrict__ dst,
    int nsrc, int ldsrc) {
  int idx = blockIdx.x * 256 + threadIdx.x;
  int m = idx >> 10, c = idx & 1023;
  dst[idx] = (c < nsrc) ? f2bf(src[(size_t)m * ldsrc + c]) : (unsigned short)0;
}

// --------------------------------------- weight transpose + bf16 (padded) ---
// dst[n][k] (ld 1024) = src[k][n]; zero outside (ksrc x nsrc). grid (32,32).
__global__ __launch_bounds__(256) void wtrans_kernel(
    const float* __restrict__ src, unsigned short* __restrict__ dst,
    int ksrc, int nsrc, int ldsrc) {
  __shared__ float tile[32][33];
  int k0 = blockIdx.x * 32, n0 = blockIdx.y * 32;
  int tx = threadIdx.x & 31, ty = threadIdx.x >> 5;
  for (int i = 0; i < 32; i += 8) {
    int k = k0 + ty + i, n = n0 + tx;
    tile[ty + i][tx] = (k < ksrc && n < nsrc) ? src[(size_t)k * ldsrc + n] : 0.f;
  }
  __syncthreads();
  for (int i = 0; i < 32; i += 8) {
    int n = n0 + ty + i, k = k0 + tx;
    dst[(size_t)n * 1024 + k] = f2bf(tile[tx][ty + i]);
  }
}

// ------------------------------------------------------- bf16 MFMA GEMM -----
// C[M][ldc slice] = A[M][1024]bf16 @ Bt[n][k]bf16^T + bias. 128x128 tile,
// BK=32, 4 waves each 64x64 via 4x4 of 16x16x32 MFMA, global_load_lds w=16.
// bias chosen per 1024-col slice (b0/b1/b2); store only (n&1023) < nact.
// elu+1 applied for n < elu_ncut. out_bf16: C is bf16. Else fp32 with
// mode 0: C=val, 1: C=g*val, 2: C+=g*val (g = gw[m*4+expert]).
__global__ __launch_bounds__(256) void gemm_mfma(
    const unsigned short* __restrict__ A, const unsigned short* __restrict__ Bt,
    const float* __restrict__ b0, const float* __restrict__ b1,
    const float* __restrict__ b2, void* __restrict__ Cv, int ldc,
    int nact, int elu_ncut, int out_bf16, int mode,
    const float* __restrict__ gw, int expert) {
  constexpr int K = 1024;
  __shared__ __align__(16) unsigned short As[128 * 32];
  __shared__ __align__(16) unsigned short Bs[128 * 32];
  int tid = threadIdx.x, wave = tid >> 6, lane = tid & 63;
  int quad = lane >> 4, lrow = lane & 15;
  int rw = (wave >> 1) * 64, cw = (wave & 1) * 64;
  int m0 = blockIdx.y * 128, n0 = blockIdx.x * 128;
  // staging: wave covers rows [wave*32, wave*32+32); lane i handles
  // row = wave*32 (+16 for 2nd instr) + i/4, k-chunk (i%4)*8 (16B)
  int srow = wave * 32 + (lane >> 2);
  int scol = (lane & 3) * 8;
  const unsigned short* gA = A + (size_t)(m0 + srow) * K + scol;
  const unsigned short* gB = Bt + (size_t)(n0 + srow) * K + scol;
  unsigned short* lA = &As[wave * 1024];  // wave-uniform LDS base
  unsigned short* lB = &Bs[wave * 1024];
  f32x4 acc[4][4];
#pragma unroll
  for (int mt = 0; mt < 4; ++mt)
#pragma unroll
    for (int nt = 0; nt < 4; ++nt) acc[mt][nt] = (f32x4){0.f, 0.f, 0.f, 0.f};

  for (int k0 = 0; k0 < K; k0 += 32) {
    gld16(gA + k0, lA);
    gld16(gA + 16 * K + k0, lA + 512);
    gld16(gB + k0, lB);
    gld16(gB + 16 * K + k0, lB + 512);
    __syncthreads();  // compiler emits vmcnt(0) drain before barrier
    bf16x8 af[4], bfr[4];
#pragma unroll
    for (int t = 0; t < 4; ++t) {
      af[t]  = *(const bf16x8*)&As[(rw + t * 16 + lrow) * 32 + quad * 8];
      bfr[t] = *(const bf16x8*)&Bs[(cw + t * 16 + lrow) * 32 + quad * 8];
    }
#pragma unroll
    for (int mt = 0; mt < 4; ++mt)
#pragma unroll
      for (int nt = 0; nt < 4; ++nt)
        acc[mt][nt] = __builtin_amdgcn_mfma_f32_16x16x32_bf16(
            af[mt], bfr[nt], acc[mt][nt], 0, 0, 0);
    __syncthreads();
  }
  // epilogue: D[row=quad*4+r][col=lrow] per 16x16 tile (m89-verified layout)
#pragma unroll
  for (int nt = 0; nt < 4; ++nt) {
    int n = n0 + cw + nt * 16 + lrow;
    int slice = n >> 10, noff = n & 1023;
    if (noff >= nact) continue;
    const float* bp = (slice == 0) ? b0 : (slice == 1) ? b1 : b2;
    float bias = bp[noff];
    bool do_elu = n < elu_ncut;
#pragma unroll
    for (int mt = 0; mt < 4; ++mt) {
      int mb = m0 + rw + mt * 16 + quad * 4;
#pragma unroll
      for (int r = 0; r < 4; ++r) {
        int m = mb + r;
        float val = acc[mt][nt][r] + bias;
        if (do_elu) val = (val > 0.f) ? val + 1.f : expf(val);
        size_t ci = (size_t)m * ldc + n;
        if (out_bf16) {
          ((unsigned short*)Cv)[ci] = f2bf(val);
        } else {
          float* C = (float*)Cv;
          if (mode == 0) C[ci] = val;
          else {
            float g = gw[m * 4 + expert];
            if (mode == 1) C[ci] = g * val;
            else           C[ci] += g * val;
          }
        }
      }
    }
  }
}

// ----------------------------------------------- std / local attention ------
template <int HD>
__global__ __launch_bounds__(256) void attn_kernel(
    const unsigned short* __restrict__ q, const unsigned short* __restrict__ k,
    const unsigned short* __restrict__ v, const int* __restrict__ amask,
    float* __restrict__ ao, int ldq, int ldo, int w2) {
  constexpr int QT = 32, KT = 32;
  constexpr int NCOL = (HD + 7) / 8;
  constexpr int PHD = NCOL * 8;
  __shared__ float Qs[QT][PHD + 1];
  __shared__ float Ks[KT][PHD + 1];
  __shared__ float Vs[KT][PHD + 1];
  __shared__ float Ss[QT][KT + 1];
  __shared__ float mrow[QT], lrow_[QT], alph[QT];
  int tid = threadIdx.x;
  int q0 = blockIdx.x * QT;
  int h = blockIdx.y;
  int b = blockIdx.z;
  const float scale = rsqrtf((float)HD);
  size_t baseq = ((size_t)b * S_) * ldq + (size_t)h * HD;
  size_t baseo = ((size_t)b * S_) * ldo + (size_t)h * HD;

  for (int idx = tid; idx < QT * PHD; idx += 256) {
    int r = idx / PHD, d = idx % PHD;
    Qs[r][d] = (d < HD) ? bf2f(q[baseq + (size_t)(q0 + r) * ldq + d]) : 0.f;
  }
  if (tid < QT) { mrow[tid] = -INFINITY; lrow_[tid] = 0.f; }
  float acc[NCOL];
#pragma unroll
  for (int c = 0; c < NCOL; ++c) acc[c] = 0.f;
  int r = tid % 32, grp = tid / 32;
  __syncthreads();

  for (int j0 = 0; j0 < S_; j0 += KT) {
    if (j0 > q0 + QT - 1 + w2) break;
    if (j0 + KT - 1 < q0 - w2) continue;
    for (int idx = tid; idx < KT * PHD; idx += 256) {
      int rr = idx / PHD, d = idx % PHD;
      float kv_ = 0.f, vv_ = 0.f;
      if (d < HD) {
        size_t g = baseq + (size_t)(j0 + rr) * ldq + d;
        kv_ = bf2f(k[g]); vv_ = bf2f(v[g]);
      }
      Ks[rr][d] = kv_;
      Vs[rr][d] = vv_;
    }
    __syncthreads();
    {
      int qi = tid % 32;
      int kjb = (tid / 32) * 4;
      float s0 = 0.f, s1 = 0.f, s2 = 0.f, s3 = 0.f;
      for (int d = 0; d < HD; ++d) {
        float qv = Qs[qi][d];
        s0 += qv * Ks[kjb + 0][d];
        s1 += qv * Ks[kjb + 1][d];
        s2 += qv * Ks[kjb + 2][d];
        s3 += qv * Ks[kjb + 3][d];
      }
      float sv[4] = {s0, s1, s2, s3};
#pragma unroll
      for (int jj = 0; jj < 4; ++jj) {
        int kj = kjb + jj;
        int dj = (j0 + kj) - (q0 + qi);
        bool ok = (dj <= w2) && (dj >= -w2);
        if (amask[b * S_ + j0 + kj] == 0) ok = false;
        Ss[qi][kj] = ok ? sv[jj] * scale : -1e30f;
      }
    }
    __syncthreads();
    if (tid < QT) {
      int qi = tid;
      float mold = mrow[qi];
      float mx = mold;
#pragma unroll
      for (int kj = 0; kj < KT; ++kj) mx = fmaxf(mx, Ss[qi][kj]);
      float alpha;
      if (mold <= -1e29f) alpha = (mx <= -1e29f) ? 1.f : 0.f;
      else                alpha = expf(mold - mx);
      float lsum = 0.f;
#pragma unroll
      for (int kj = 0; kj < KT; ++kj) {
        float sv = Ss[qi][kj];
        float p = (sv <= -1e29f) ? 0.f : expf(sv - mx);
        Ss[qi][kj] = p;
        lsum += p;
      }
      mrow[qi] = mx;
      lrow_[qi] = lrow_[qi] * alpha + lsum;
      alph[qi] = alpha;
    }
    __syncthreads();
    {
      float alpha = alph[r];
#pragma unroll
      for (int c = 0; c < NCOL; ++c) acc[c] *= alpha;
      for (int kj = 0; kj < KT; ++kj) {
        float p = Ss[r][kj];
#pragma unroll
        for (int c = 0; c < NCOL; ++c) acc[c] += p * Vs[kj][grp * NCOL + c];
      }
    }
    __syncthreads();
  }
  float l = lrow_[r];
  float inv = (l > 0.f) ? 1.f / l : 0.f;
#pragma unroll
  for (int c = 0; c < NCOL; ++c) {
    int d = grp * NCOL + c;
    if (d < HD) ao[baseo + (size_t)(q0 + r) * ldo + d] = acc[c] * inv;
  }
}

// ------------------------------------------------------ linear attention ----
__global__ __launch_bounds__(256) void linkv_kernel(
    const unsigned short* __restrict__ k, const unsigned short* __restrict__ v,
    float* __restrict__ kv, float* __restrict__ ksum, int ld) {
  constexpr int HD = 128;
  int h = blockIdx.x, b = blockIdx.y;
  int tid = threadIdx.x;
  __shared__ float ks[8][HD], vs[8][HD];
  int dr = tid / 2, c0 = (tid % 2) * 64;
  float acc[64];
#pragma unroll
  for (int c = 0; c < 64; ++c) acc[c] = 0.f;
  float ksacc = 0.f;
  size_t base = ((size_t)b * S_) * ld + (size_t)h * HD;
  for (int s0 = 0; s0 < S_; s0 += 8) {
    for (int idx = tid; idx < 8 * HD; idx += 256) {
      int rr = idx / HD, d = idx % HD;
      size_t g = base + (size_t)(s0 + rr) * ld + d;
      ks[rr][d] = bf2f(k[g]);
      vs[rr][d] = bf2f(v[g]);
    }
    __syncthreads();
#pragma unroll
    for (int rr = 0; rr < 8; ++rr) {
      float kval = ks[rr][dr];
#pragma unroll
      for (int c = 0; c < 64; ++c) acc[c] += kval * vs[rr][c0 + c];
    }
    if (tid < HD) {
#pragma unroll
      for (int rr = 0; rr < 8; ++rr) ksacc += ks[rr][tid];
    }
    __syncthreads();
  }
  size_t kvbase = (size_t)(b * 8 + h) * HD * HD;
  for (int c = 0; c < 64; ++c) kv[kvbase + (size_t)dr * HD + c0 + c] = acc[c];
  if (tid < HD) ksum[(size_t)(b * 8 + h) * HD + tid] = ksacc;
}

__global__ __launch_bounds__(256) void linattn_kernel(
    const unsigned short* __restrict__ q, const float* __restrict__ kv,
    const float* __restrict__ ksum, float* __restrict__ ao, int ldq, int ldo) {
  constexpr int HD = 128;
  int q0 = blockIdx.x * 32;
  int h = blockIdx.y, b = blockIdx.z;
  int tid = threadIdx.x;
  __shared__ float Qs[32][HD + 1];
  __shared__ float den[32];
  size_t baseq = ((size_t)b * S_) * ldq + (size_t)h * HD;
  size_t baseo = ((size_t)b * S_) * ldo + (size_t)h * HD;
  for (int idx = tid; idx < 32 * HD; idx += 256) {
    int r = idx / HD, d = idx % HD;
    Qs[r][d] = bf2f(q[baseq + (size_t)(q0 + r) * ldq + d]);
  }
  __syncthreads();
  int r = tid % 32, grp = tid / 32;
  const float* kvb = kv + (size_t)(b * 8 + h) * HD * HD;
  float acc[16];
#pragma unroll
  for (int c = 0; c < 16; ++c) acc[c] = 0.f;
  for (int d = 0; d < HD; ++d) {
    float qv = Qs[r][d];
    const float* kvr = kvb + (size_t)d * HD + grp * 16;
#pragma unroll
    for (int c = 0; c < 16; ++c) acc[c] += qv * kvr[c];
  }
  if (tid < 32) {
    const float* ks = ksum + (size_t)(b * 8 + h) * HD;
    float dsum = 0.f;
    for (int d = 0; d < HD; ++d) dsum += Qs[tid][d] * ks[d];
    den[tid] = dsum + 1e-6f;
  }
  __syncthreads();
  float inv = 1.f / den[r];
#pragma unroll
  for (int c = 0; c < 16; ++c)
    ao[baseo + (size_t)(q0 + r) * ldo + grp * 16 + c] = acc[c] * inv;
}

// ---------------------------------------------------------------- launch ----
extern "C" void kernel_launch(void* const* d_in, const int* in_sizes, int n_in,
                              void* d_out, int out_size, void* d_ws, size_t ws_size,
                              hipStream_t stream) {
  const float* x = (const float*)d_in[0];
  const float* Wg = (const float*)d_in[1];
  const int* amask = (const int*)d_in[34];
  float* out = (float*)d_out;
  char* ws = (char*)d_ws;
  // workspace layout (68 MB; round-0 proved >=80 MB available)
  float* gw            = (float*)(ws + 0);                     // 64 KB
  float* kv            = (float*)(ws + (1ull << 20));          // 2 MB
  float* ksum          = (float*)(ws + (3ull << 20) + (1ull << 19));
  unsigned short* xb   = (unsigned short*)(ws + (4ull << 20)); // 8 MB
  unsigned short* qkvT = (unsigned short*)(ws + (12ull << 20));// 6 MB (reused/expert)
  unsigned short* woT  = (unsigned short*)(ws + (18ull << 20));// 2 MB
  unsigned short* qkv  = (unsigned short*)(ws + (20ull << 20));// 24 MB [4096][3072]
  float* ao            = (float*)(ws + (44ull << 20));         // 16 MB [4096][1024]
  unsigned short* aob  = (unsigned short*)(ws + (60ull << 20));// 8 MB

  conv_kernel<<<16384, 256, 0, stream>>>(x, xb, 1024, 1024);
  gate_kernel<<<4096, 64, 0, stream>>>(x, Wg, gw);

  const int nhs[4] = {8, 12, 8, 8};
  for (int e = 0; e < 4; ++e) {
    const float* Wq = (const float*)d_in[2 + 8 * e + 0];
    const float* bq = (const float*)d_in[2 + 8 * e + 1];
    const float* Wk = (const float*)d_in[2 + 8 * e + 2];
    const float* bk = (const float*)d_in[2 + 8 * e + 3];
    const float* Wv = (const float*)d_in[2 + 8 * e + 4];
    const float* bv = (const float*)d_in[2 + 8 * e + 5];
    const float* Wo = (const float*)d_in[2 + 8 * e + 6];
    const float* bo = (const float*)d_in[2 + 8 * e + 7];
    int nh = nhs[e];
    int hd = H_ / nh;   // 128 or 85
    int pd = nh * hd;   // 1024 or 1020

    // bf16 transposed (padded) weights
    wtrans_kernel<<<dim3(32, 32), 256, 0, stream>>>(Wq, qkvT,                1024, pd, pd);
    wtrans_kernel<<<dim3(32, 32), 256, 0, stream>>>(Wk, qkvT + (1 << 20),    1024, pd, pd);
    wtrans_kernel<<<dim3(32, 32), 256, 0, stream>>>(Wv, qkvT + (2 << 20),    1024, pd, pd);
    wtrans_kernel<<<dim3(32, 32), 256, 0, stream>>>(Wo, woT,                 pd, 1024, 1024);

    // fused QKV projection: [4096][3072] bf16 out
    gemm_mfma<<<dim3(24, 32), 256, 0, stream>>>(
        xb, qkvT, bq, bk, bv, qkv, 3072,
        (pd == 1020) ? 1020 : 1024, (e == 2) ? 2048 : 0, 1, 0, nullptr, 0);

    const unsigned short* qb = qkv;
    const unsigned short* kb = qkv + 1024;
    const unsigned short* vb = qkv + 2048;
    if (e == 2) {
      linkv_kernel<<<dim3(8, B_), 256, 0, stream>>>(kb, vb, kv, ksum, 3072);
      linattn_kernel<<<dim3(S_ / 32, 8, B_), 256, 0, stream>>>(qb, kv, ksum, ao, 3072, 1024);
    } else {
      int w2 = (e == 3) ? 32 : (1 << 20);
      dim3 agrid(S_ / 32, nh, B_);
      if (hd == 128)
        attn_kernel<128><<<agrid, 256, 0, stream>>>(qb, kb, vb, amask, ao, 3072, 1024, w2);
      else
        attn_kernel<85><<<agrid, 256, 0, stream>>>(qb, kb, vb, amask, ao, 3072, 1024, w2);
    }

    conv_kernel<<<16384, 256, 0, stream>>>(ao, aob, pd, 1024);

    // output projection + gate, accumulate into out
    gemm_mfma<<<dim3(8, 32), 256, 0, stream>>>(
        aob, woT, bo, bo, bo, out, 1024, 1024, 0, 0, (e == 0) ? 1 : 2, gw, e);
  }
}

// Round 3
// 1997.808 us; speedup vs baseline: 3.3079x; 1.8032x over previous
//
#include <hip/hip_runtime.h>
#include <cmath>

#define B_ 4
#define S_ 1024
#define H_ 1024

typedef short bf16x8 __attribute__((ext_vector_type(8)));
typedef float f32x4 __attribute__((ext_vector_type(4)));
typedef _Float16 half4 __attribute__((ext_vector_type(4)));

__device__ __forceinline__ unsigned short f2bf(float f) {
  unsigned u = __float_as_uint(f);
  u += 0x7fff + ((u >> 16) & 1);  // RTNE
  return (unsigned short)(u >> 16);
}
__device__ __forceinline__ float bf2f(unsigned short h) {
  return __uint_as_float(((unsigned)h) << 16);
}
__device__ __forceinline__ void gld16(const void* g, void* l) {
  __builtin_amdgcn_global_load_lds(
      (const __attribute__((address_space(1))) unsigned int*)g,
      (__attribute__((address_space(3))) unsigned int*)l, 16, 0, 0);
}

// ---------------------------------------------------------------- gating ----
__global__ __launch_bounds__(64) void gate_kernel(
    const float* __restrict__ x, const float* __restrict__ Wg,
    float* __restrict__ gw) {
  int t = blockIdx.x;
  int lane = threadIdx.x;
  const float* xr = x + (size_t)t * H_;
  float a0 = 0.f, a1 = 0.f, a2 = 0.f, a3 = 0.f;
  for (int h = lane; h < H_; h += 64) {
    float xv = xr[h];
    const float* wr = Wg + h * 4;
    a0 += xv * wr[0]; a1 += xv * wr[1]; a2 += xv * wr[2]; a3 += xv * wr[3];
  }
  for (int off = 32; off > 0; off >>= 1) {
    a0 += __shfl_down(a0, off);
    a1 += __shfl_down(a1, off);
    a2 += __shfl_down(a2, off);
    a3 += __shfl_down(a3, off);
  }
  if (lane == 0) {
    float v[4] = {a0, a1, a2, a3};
    int i0 = 0; float b0 = v[0];
    for (int e = 1; e < 4; ++e) if (v[e] > b0) { b0 = v[e]; i0 = e; }
    int i1 = -1; float b1 = -INFINITY;
    for (int e = 0; e < 4; ++e) { if (e == i0) continue; if (v[e] > b1) { b1 = v[e]; i1 = e; } }
    float e1v = expf(b1 - b0);
    float w0 = 1.f / (1.f + e1v);
    float w1 = e1v / (1.f + e1v);
    float o[4] = {0.f, 0.f, 0.f, 0.f};
    o[i0] = w0; o[i1] = w1;
    float* g = gw + t * 4;
    g[0] = o[0]; g[1] = o[1]; g[2] = o[2]; g[3] = o[3];
  }
}

// -------------------------------------------------------- fp32 -> bf16 ------
__global__ __launch_bounds__(256) void conv_kernel(
    const float* __restrict__ src, unsigned short* __restrict__ dst,
    int nsrc, int ldsrc) {
  int idx = blockIdx.x * 256 + threadIdx.x;
  int m = idx >> 10, c = idx & 1023;
  dst[idx] = (c < nsrc) ? f2bf(src[(size_t)m * ldsrc + c]) : (unsigned short)0;
}

// zero bf16 cols [c0,1024) of dst[4096][1024]
__global__ __launch_bounds__(256) void zpad_kernel(unsigned short* dst, int c0) {
  int w = 1024 - c0;
  int idx = blockIdx.x * 256 + threadIdx.x;
  int m = idx / w, c = idx % w;
  if (m < 4096) dst[(size_t)m * 1024 + c0 + c] = 0;
}

// --------------------------------------- weight transpose + bf16 (padded) ---
__global__ __launch_bounds__(256) void wtrans_kernel(
    const float* __restrict__ src, unsigned short* __restrict__ dst,
    int ksrc, int nsrc, int ldsrc) {
  __shared__ float tile[32][33];
  int k0 = blockIdx.x * 32, n0 = blockIdx.y * 32;
  int tx = threadIdx.x & 31, ty = threadIdx.x >> 5;
  for (int i = 0; i < 32; i += 8) {
    int k = k0 + ty + i, n = n0 + tx;
    tile[ty + i][tx] = (k < ksrc && n < nsrc) ? src[(size_t)k * ldsrc + n] : 0.f;
  }
  __syncthreads();
  for (int i = 0; i < 32; i += 8) {
    int n = n0 + ty + i, k = k0 + tx;
    dst[(size_t)n * 1024 + k] = f2bf(tile[tx][ty + i]);
  }
}

// ------------------------------------------------------- bf16 MFMA GEMM -----
__global__ __launch_bounds__(256) void gemm_mfma(
    const unsigned short* __restrict__ A, const unsigned short* __restrict__ Bt,
    const float* __restrict__ b0, const float* __restrict__ b1,
    const float* __restrict__ b2, void* __restrict__ Cv, int ldc,
    int nact, int elu_ncut, int out_bf16, int mode,
    const float* __restrict__ gw, int expert) {
  constexpr int K = 1024;
  __shared__ __align__(16) unsigned short As[128 * 32];
  __shared__ __align__(16) unsigned short Bs[128 * 32];
  int tid = threadIdx.x, wave = tid >> 6, lane = tid & 63;
  int quad = lane >> 4, lrow = lane & 15;
  int rw = (wave >> 1) * 64, cw = (wave & 1) * 64;
  int m0 = blockIdx.y * 128, n0 = blockIdx.x * 128;
  int srow = wave * 32 + (lane >> 2);
  int scol = (lane & 3) * 8;
  const unsigned short* gA = A + (size_t)(m0 + srow) * K + scol;
  const unsigned short* gB = Bt + (size_t)(n0 + srow) * K + scol;
  unsigned short* lA = &As[wave * 1024];
  unsigned short* lB = &Bs[wave * 1024];
  f32x4 acc[4][4];
#pragma unroll
  for (int mt = 0; mt < 4; ++mt)
#pragma unroll
    for (int nt = 0; nt < 4; ++nt) acc[mt][nt] = (f32x4){0.f, 0.f, 0.f, 0.f};

  for (int k0 = 0; k0 < K; k0 += 32) {
    gld16(gA + k0, lA);
    gld16(gA + 16 * K + k0, lA + 512);
    gld16(gB + k0, lB);
    gld16(gB + 16 * K + k0, lB + 512);
    __syncthreads();
    bf16x8 af[4], bfr[4];
#pragma unroll
    for (int t = 0; t < 4; ++t) {
      af[t]  = *(const bf16x8*)&As[(rw + t * 16 + lrow) * 32 + quad * 8];
      bfr[t] = *(const bf16x8*)&Bs[(cw + t * 16 + lrow) * 32 + quad * 8];
    }
#pragma unroll
    for (int mt = 0; mt < 4; ++mt)
#pragma unroll
      for (int nt = 0; nt < 4; ++nt)
        acc[mt][nt] = __builtin_amdgcn_mfma_f32_16x16x32_bf16(
            af[mt], bfr[nt], acc[mt][nt], 0, 0, 0);
    __syncthreads();
  }
#pragma unroll
  for (int nt = 0; nt < 4; ++nt) {
    int n = n0 + cw + nt * 16 + lrow;
    int slice = n >> 10, noff = n & 1023;
    if (noff >= nact) continue;
    const float* bp = (slice == 0) ? b0 : (slice == 1) ? b1 : b2;
    float bias = bp[noff];
    bool do_elu = n < elu_ncut;
#pragma unroll
    for (int mt = 0; mt < 4; ++mt) {
      int mb = m0 + rw + mt * 16 + quad * 4;
#pragma unroll
      for (int r = 0; r < 4; ++r) {
        int m = mb + r;
        float val = acc[mt][nt][r] + bias;
        if (do_elu) val = (val > 0.f) ? val + 1.f : expf(val);
        size_t ci = (size_t)m * ldc + n;
        if (out_bf16) {
          ((unsigned short*)Cv)[ci] = f2bf(val);
        } else {
          float* C = (float*)Cv;
          if (mode == 0) C[ci] = val;
          else {
            float g = gw[m * 4 + expert];
            if (mode == 1) C[ci] = g * val;
            else           C[ci] += g * val;
          }
        }
      }
    }
  }
}

// --------------------------------------------- MFMA flash attention ---------
// Transposed-score trick: S^T = K@Q^T via 16x16x32 bf16 MFMA gives
// query=lane&15 (col), key=quad*4+r (row). Softmax rows reduce with
// shfl_xor(16,32). Exp'd S^T frag IS the A-operand of 16x16x16 f16 MFMA
// (m=lane&15, k=quad*4+j) -> PV with no cross-lane movement. V^T in LDS fp16.
// QT=64 (4 waves x 16 queries), KT=32. Output bf16 (ld ldo).
template <int HD>
__global__ __launch_bounds__(256) void attn_mfma(
    const unsigned short* __restrict__ q, const unsigned short* __restrict__ k,
    const unsigned short* __restrict__ v, const int* __restrict__ amask,
    unsigned short* __restrict__ ao, int ldq, int ldo, int w2) {
  constexpr int HDP = (HD + 31) & ~31;  // 128 or 96
  constexpr int DCH = HDP / 32;         // 4 or 3
  constexpr int NDT = HDP / 16;         // 8 or 6
  constexpr int QT = 64, KT = 32;
  constexpr int KLD = HDP + 8;          // shorts; 2-way-max bank aliasing
  constexpr int VLD = KT + 4;           // 36 shorts: 8B-aligned rows, spread banks
  __shared__ __align__(16) unsigned short Ks[KT * KLD];
  __shared__ __align__(16) _Float16 Vt[HDP * VLD];
  __shared__ unsigned char am[S_];
  int tid = threadIdx.x, wave = tid >> 6, lane = tid & 63;
  int quad = lane >> 4, l15 = lane & 15;
  int q0 = blockIdx.x * QT, h = blockIdx.y, b = blockIdx.z;
  const float scale = rsqrtf((float)HD);
  size_t baseq = ((size_t)b * S_) * ldq + (size_t)h * HD;
  size_t baseo = ((size_t)b * S_) * ldo + (size_t)h * HD;

  for (int i = tid; i < S_; i += 256) am[i] = (unsigned char)(amask[b * S_ + i] != 0);

  // Q fragments in registers: lane holds Q[query=l15][d=c*32+quad*8+j]
  int qrow = q0 + wave * 16 + l15;  // global query index for this lane
  bf16x8 qf[DCH];
#pragma unroll
  for (int c = 0; c < DCH; ++c)
#pragma unroll
    for (int j = 0; j < 8; ++j) {
      int d = c * 32 + quad * 8 + j;
      qf[c][j] = (d < HD) ? (short)q[baseq + (size_t)qrow * ldq + d] : (short)0;
    }

  float m_run = -1e30f, l_run = 0.f;
  f32x4 accd[NDT];
#pragma unroll
  for (int dt = 0; dt < NDT; ++dt) accd[dt] = (f32x4){0.f, 0.f, 0.f, 0.f};

  for (int j0 = 0; j0 < S_; j0 += KT) {
    if (j0 > q0 + QT - 1 + w2) break;
    if (j0 + KT - 1 < q0 - w2) continue;
    __syncthreads();  // previous iteration's LDS reads done
    // stage K (row-major, zero-padded d) and V^T (fp16)
    for (int idx = tid; idx < KT * HDP; idx += 256) {
      int key = idx / HDP, d = idx % HDP;
      unsigned short kv_ = 0; float vv = 0.f;
      if (d < HD) {
        size_t g = baseq + (size_t)(j0 + key) * ldq + d;
        kv_ = k[g];
        vv = bf2f(v[g]);
      }
      Ks[key * KLD + d] = kv_;
      Vt[d * VLD + key] = (_Float16)vv;
    }
    __syncthreads();
    // S^T fragments: two 16-key tiles
    f32x4 sf[2];
    sf[0] = (f32x4){0.f, 0.f, 0.f, 0.f};
    sf[1] = (f32x4){0.f, 0.f, 0.f, 0.f};
#pragma unroll
    for (int kt = 0; kt < 2; ++kt)
#pragma unroll
      for (int c = 0; c < DCH; ++c) {
        bf16x8 kf = *(const bf16x8*)&Ks[(kt * 16 + l15) * KLD + c * 32 + quad * 8];
        sf[kt] = __builtin_amdgcn_mfma_f32_16x16x32_bf16(kf, qf[c], sf[kt], 0, 0, 0);
      }
    // mask + online softmax (state replicated across quads, query = l15)
    float sval[2][4];
    bool vld[2][4];
    float mx = -1e30f;
#pragma unroll
    for (int kt = 0; kt < 2; ++kt)
#pragma unroll
      for (int r = 0; r < 4; ++r) {
        int key = j0 + kt * 16 + quad * 4 + r;
        int dj = key - qrow;
        bool ok = (dj <= w2) && (dj >= -w2) && am[key];
        float s = ok ? sf[kt][r] * scale : -1e30f;
        sval[kt][r] = s;
        vld[kt][r] = ok;
        mx = fmaxf(mx, s);
      }
    mx = fmaxf(mx, __shfl_xor(mx, 16));
    mx = fmaxf(mx, __shfl_xor(mx, 32));
    float m_new = fmaxf(m_run, mx);
    float psum = 0.f;
    float pv[2][4];
#pragma unroll
    for (int kt = 0; kt < 2; ++kt)
#pragma unroll
      for (int r = 0; r < 4; ++r) {
        float p = vld[kt][r] ? expf(sval[kt][r] - m_new) : 0.f;
        pv[kt][r] = p;
        psum += p;
      }
    psum += __shfl_xor(psum, 16);
    psum += __shfl_xor(psum, 32);
    float alpha = expf(m_run - m_new);  // m_run=-1e30 -> 0 (or 1 when both; acc=0)
    m_run = m_new;
    l_run = l_run * alpha + psum;
    // broadcast alpha to O-frag rows (row query = quad*4+r)
    float aR[4];
#pragma unroll
    for (int r = 0; r < 4; ++r)
      aR[r] = __shfl(alpha, (lane & 48) | (quad * 4 + r));
#pragma unroll
    for (int dt = 0; dt < NDT; ++dt)
#pragma unroll
      for (int r = 0; r < 4; ++r) accd[dt][r] *= aR[r];
    // P fragments (fp16) and PV
    half4 pf0, pf1;
#pragma unroll
    for (int r = 0; r < 4; ++r) { pf0[r] = (_Float16)pv[0][r]; pf1[r] = (_Float16)pv[1][r]; }
#pragma unroll
    for (int dt = 0; dt < NDT; ++dt) {
      half4 vf0 = *(const half4*)&Vt[(dt * 16 + l15) * VLD + quad * 4];
      accd[dt] = __builtin_amdgcn_mfma_f32_16x16x16f16(pf0, vf0, accd[dt], 0, 0, 0);
      half4 vf1 = *(const half4*)&Vt[(dt * 16 + l15) * VLD + 16 + quad * 4];
      accd[dt] = __builtin_amdgcn_mfma_f32_16x16x16f16(pf1, vf1, accd[dt], 0, 0, 0);
    }
  }
  // finalize: O[row=q0+wave*16+quad*4+r][col=dt*16+l15]
  float linv = (l_run > 0.f) ? 1.f / l_run : 0.f;
  float lR[4];
#pragma unroll
  for (int r = 0; r < 4; ++r)
    lR[r] = __shfl(linv, (lane & 48) | (quad * 4 + r));
#pragma unroll
  for (int dt = 0; dt < NDT; ++dt) {
    int d = dt * 16 + l15;
    if (d >= HD) continue;
#pragma unroll
    for (int r = 0; r < 4; ++r) {
      int row = q0 + wave * 16 + quad * 4 + r;
      ao[baseo + (size_t)row * ldo + d] = f2bf(accd[dt][r] * lR[r]);
    }
  }
}

// ------------------------------------------------------ linear attention ----
__global__ __launch_bounds__(256) void linkv_kernel(
    const unsigned short* __restrict__ k, const unsigned short* __restrict__ v,
    float* __restrict__ kv, float* __restrict__ ksum, int ld) {
  constexpr int HD = 128;
  int h = blockIdx.x, b = blockIdx.y;
  int tid = threadIdx.x;
  __shared__ float ks[8][HD], vs[8][HD];
  int dr = tid / 2, c0 = (tid % 2) * 64;
  float acc[64];
#pragma unroll
  for (int c = 0; c < 64; ++c) acc[c] = 0.f;
  float ksacc = 0.f;
  size_t base = ((size_t)b * S_) * ld + (size_t)h * HD;
  for (int s0 = 0; s0 < S_; s0 += 8) {
    for (int idx = tid; idx < 8 * HD; idx += 256) {
      int rr = idx / HD, d = idx % HD;
      size_t g = base + (size_t)(s0 + rr) * ld + d;
      ks[rr][d] = bf2f(k[g]);
      vs[rr][d] = bf2f(v[g]);
    }
    __syncthreads();
#pragma unroll
    for (int rr = 0; rr < 8; ++rr) {
      float kval = ks[rr][dr];
#pragma unroll
      for (int c = 0; c < 64; ++c) acc[c] += kval * vs[rr][c0 + c];
    }
    if (tid < HD) {
#pragma unroll
      for (int rr = 0; rr < 8; ++rr) ksacc += ks[rr][tid];
    }
    __syncthreads();
  }
  size_t kvbase = (size_t)(b * 8 + h) * HD * HD;
  for (int c = 0; c < 64; ++c) kv[kvbase + (size_t)dr * HD + c0 + c] = acc[c];
  if (tid < HD) ksum[(size_t)(b * 8 + h) * HD + tid] = ksacc;
}

__global__ __launch_bounds__(256) void linattn_kernel(
    const unsigned short* __restrict__ q, const float* __restrict__ kv,
    const float* __restrict__ ksum, unsigned short* __restrict__ ao,
    int ldq, int ldo) {
  constexpr int HD = 128;
  int q0 = blockIdx.x * 32;
  int h = blockIdx.y, b = blockIdx.z;
  int tid = threadIdx.x;
  __shared__ float Qs[32][HD + 1];
  __shared__ float den[32];
  size_t baseq = ((size_t)b * S_) * ldq + (size_t)h * HD;
  size_t baseo = ((size_t)b * S_) * ldo + (size_t)h * HD;
  for (int idx = tid; idx < 32 * HD; idx += 256) {
    int r = idx / HD, d = idx % HD;
    Qs[r][d] = bf2f(q[baseq + (size_t)(q0 + r) * ldq + d]);
  }
  __syncthreads();
  int r = tid % 32, grp = tid / 32;
  const float* kvb = kv + (size_t)(b * 8 + h) * HD * HD;
  float acc[16];
#pragma unroll
  for (int c = 0; c < 16; ++c) acc[c] = 0.f;
  for (int d = 0; d < HD; ++d) {
    float qv = Qs[r][d];
    const float* kvr = kvb + (size_t)d * HD + grp * 16;
#pragma unroll
    for (int c = 0; c < 16; ++c) acc[c] += qv * kvr[c];
  }
  if (tid < 32) {
    const float* ks = ksum + (size_t)(b * 8 + h) * HD;
    float dsum = 0.f;
    for (int d = 0; d < HD; ++d) dsum += Qs[tid][d] * ks[d];
    den[tid] = dsum + 1e-6f;
  }
  __syncthreads();
  float inv = 1.f / den[r];
#pragma unroll
  for (int c = 0; c < 16; ++c)
    ao[baseo + (size_t)(q0 + r) * ldo + grp * 16 + c] = f2bf(acc[c] * inv);
}

// ---------------------------------------------------------------- launch ----
extern "C" void kernel_launch(void* const* d_in, const int* in_sizes, int n_in,
                              void* d_out, int out_size, void* d_ws, size_t ws_size,
                              hipStream_t stream) {
  const float* x = (const float*)d_in[0];
  const float* Wg = (const float*)d_in[1];
  const int* amask = (const int*)d_in[34];
  float* out = (float*)d_out;
  char* ws = (char*)d_ws;
  float* gw            = (float*)(ws + 0);                     // 64 KB
  float* kv            = (float*)(ws + (1ull << 20));          // 2 MB
  float* ksum          = (float*)(ws + (3ull << 20) + (1ull << 19));
  unsigned short* xb   = (unsigned short*)(ws + (4ull << 20)); // 8 MB
  unsigned short* qkvT = (unsigned short*)(ws + (12ull << 20));// 6 MB
  unsigned short* woT  = (unsigned short*)(ws + (18ull << 20));// 2 MB
  unsigned short* qkv  = (unsigned short*)(ws + (20ull << 20));// 24 MB [4096][3072]
  unsigned short* aob  = (unsigned short*)(ws + (44ull << 20));// 8 MB [4096][1024]

  conv_kernel<<<16384, 256, 0, stream>>>(x, xb, 1024, 1024);
  gate_kernel<<<4096, 64, 0, stream>>>(x, Wg, gw);

  const int nhs[4] = {8, 12, 8, 8};
  for (int e = 0; e < 4; ++e) {
    const float* Wq = (const float*)d_in[2 + 8 * e + 0];
    const float* bq = (const float*)d_in[2 + 8 * e + 1];
    const float* Wk = (const float*)d_in[2 + 8 * e + 2];
    const float* bk = (const float*)d_in[2 + 8 * e + 3];
    const float* Wv = (const float*)d_in[2 + 8 * e + 4];
    const float* bv = (const float*)d_in[2 + 8 * e + 5];
    const float* Wo = (const float*)d_in[2 + 8 * e + 6];
    const float* bo = (const float*)d_in[2 + 8 * e + 7];
    int nh = nhs[e];
    int hd = H_ / nh;   // 128 or 85
    int pd = nh * hd;   // 1024 or 1020

    wtrans_kernel<<<dim3(32, 32), 256, 0, stream>>>(Wq, qkvT,             1024, pd, pd);
    wtrans_kernel<<<dim3(32, 32), 256, 0, stream>>>(Wk, qkvT + (1 << 20), 1024, pd, pd);
    wtrans_kernel<<<dim3(32, 32), 256, 0, stream>>>(Wv, qkvT + (2 << 20), 1024, pd, pd);
    wtrans_kernel<<<dim3(32, 32), 256, 0, stream>>>(Wo, woT,              pd, 1024, 1024);

    gemm_mfma<<<dim3(24, 32), 256, 0, stream>>>(
        xb, qkvT, bq, bk, bv, qkv, 3072,
        (pd == 1020) ? 1020 : 1024, (e == 2) ? 2048 : 0, 1, 0, nullptr, 0);

    const unsigned short* qb = qkv;
    const unsigned short* kb = qkv + 1024;
    const unsigned short* vb = qkv + 2048;
    if (e == 2) {
      linkv_kernel<<<dim3(8, B_), 256, 0, stream>>>(kb, vb, kv, ksum, 3072);
      linattn_kernel<<<dim3(S_ / 32, 8, B_), 256, 0, stream>>>(qb, kv, ksum, aob, 3072, 1024);
    } else {
      int w2 = (e == 3) ? 32 : (1 << 20);
      dim3 agrid(S_ / 64, nh, B_);
      if (hd == 128)
        attn_mfma<128><<<agrid, 256, 0, stream>>>(qb, kb, vb, amask, aob, 3072, 1024, w2);
      else
        attn_mfma<85><<<agrid, 256, 0, stream>>>(qb, kb, vb, amask, aob, 3072, 1024, w2);
    }
    if (pd == 1020)
      zpad_kernel<<<64, 256, 0, stream>>>(aob, 1020);

    gemm_mfma<<<dim3(8, 32), 256, 0, stream>>>(
        aob, woT, bo, bo, bo, out, 1024, 1024, 0, 0, (e == 0) ? 1 : 2, gw, e);
  }
}

// Round 4
// 1009.445 us; speedup vs baseline: 6.5467x; 1.9791x over previous
//
#include <hip/hip_runtime.h>
#include <cmath>

#define B_ 4
#define S_ 1024
#define H_ 1024

typedef short bf16x8 __attribute__((ext_vector_type(8)));
typedef float f32x4 __attribute__((ext_vector_type(4)));
typedef _Float16 half4 __attribute__((ext_vector_type(4)));

__device__ __forceinline__ unsigned short f2bf(float f) {
  unsigned u = __float_as_uint(f);
  u += 0x7fff + ((u >> 16) & 1);  // RTNE
  return (unsigned short)(u >> 16);
}
__device__ __forceinline__ float bf2f(unsigned short h) {
  return __uint_as_float(((unsigned)h) << 16);
}
__device__ __forceinline__ void gld16(const void* g, void* l) {
  __builtin_amdgcn_global_load_lds(
      (const __attribute__((address_space(1))) unsigned int*)g,
      (__attribute__((address_space(3))) unsigned int*)l, 16, 0, 0);
}

// ---------------------------------------------------------------- gating ----
__global__ __launch_bounds__(64) void gate_kernel(
    const float* __restrict__ x, const float* __restrict__ Wg,
    float* __restrict__ gw) {
  int t = blockIdx.x;
  int lane = threadIdx.x;
  const float* xr = x + (size_t)t * H_;
  float a0 = 0.f, a1 = 0.f, a2 = 0.f, a3 = 0.f;
  for (int h = lane; h < H_; h += 64) {
    float xv = xr[h];
    const float* wr = Wg + h * 4;
    a0 += xv * wr[0]; a1 += xv * wr[1]; a2 += xv * wr[2]; a3 += xv * wr[3];
  }
  for (int off = 32; off > 0; off >>= 1) {
    a0 += __shfl_down(a0, off);
    a1 += __shfl_down(a1, off);
    a2 += __shfl_down(a2, off);
    a3 += __shfl_down(a3, off);
  }
  if (lane == 0) {
    float v[4] = {a0, a1, a2, a3};
    int i0 = 0; float b0 = v[0];
    for (int e = 1; e < 4; ++e) if (v[e] > b0) { b0 = v[e]; i0 = e; }
    int i1 = -1; float b1 = -INFINITY;
    for (int e = 0; e < 4; ++e) { if (e == i0) continue; if (v[e] > b1) { b1 = v[e]; i1 = e; } }
    float e1v = expf(b1 - b0);
    float w0 = 1.f / (1.f + e1v);
    float w1 = e1v / (1.f + e1v);
    float o[4] = {0.f, 0.f, 0.f, 0.f};
    o[i0] = w0; o[i1] = w1;
    float* g = gw + t * 4;
    g[0] = o[0]; g[1] = o[1]; g[2] = o[2]; g[3] = o[3];
  }
}

// -------------------------------------------------------- fp32 -> bf16 ------
__global__ __launch_bounds__(256) void conv_kernel(
    const float* __restrict__ src, unsigned short* __restrict__ dst,
    int nsrc, int ldsrc) {
  int idx = blockIdx.x * 256 + threadIdx.x;
  int m = idx >> 10, c = idx & 1023;
  dst[idx] = (c < nsrc) ? f2bf(src[(size_t)m * ldsrc + c]) : (unsigned short)0;
}

// zero bf16 cols [c0,1024) of dst[4096][1024]
__global__ __launch_bounds__(256) void zpad_kernel(unsigned short* dst, int c0) {
  int w = 1024 - c0;
  int idx = blockIdx.x * 256 + threadIdx.x;
  int m = idx / w, c = idx % w;
  if (m < 4096) dst[(size_t)m * 1024 + c0 + c] = 0;
}

// --------------------------------------- weight transpose + bf16 (padded) ---
__global__ __launch_bounds__(256) void wtrans_kernel(
    const float* __restrict__ src, unsigned short* __restrict__ dst,
    int ksrc, int nsrc, int ldsrc) {
  __shared__ float tile[32][33];
  int k0 = blockIdx.x * 32, n0 = blockIdx.y * 32;
  int tx = threadIdx.x & 31, ty = threadIdx.x >> 5;
  for (int i = 0; i < 32; i += 8) {
    int k = k0 + ty + i, n = n0 + tx;
    tile[ty + i][tx] = (k < ksrc && n < nsrc) ? src[(size_t)k * ldsrc + n] : 0.f;
  }
  __syncthreads();
  for (int i = 0; i < 32; i += 8) {
    int n = n0 + ty + i, k = k0 + tx;
    dst[(size_t)n * 1024 + k] = f2bf(tile[tx][ty + i]);
  }
}

// ------------------------------------------------------- bf16 MFMA GEMM -----
__global__ __launch_bounds__(256) void gemm_mfma(
    const unsigned short* __restrict__ A, const unsigned short* __restrict__ Bt,
    const float* __restrict__ b0, const float* __restrict__ b1,
    const float* __restrict__ b2, void* __restrict__ Cv, int ldc,
    int nact, int elu_ncut, int out_bf16, int mode,
    const float* __restrict__ gw, int expert) {
  constexpr int K = 1024;
  __shared__ __align__(16) unsigned short As[128 * 32];
  __shared__ __align__(16) unsigned short Bs[128 * 32];
  int tid = threadIdx.x, wave = tid >> 6, lane = tid & 63;
  int quad = lane >> 4, lrow = lane & 15;
  int rw = (wave >> 1) * 64, cw = (wave & 1) * 64;
  int m0 = blockIdx.y * 128, n0 = blockIdx.x * 128;
  int srow = wave * 32 + (lane >> 2);
  int scol = (lane & 3) * 8;
  const unsigned short* gA = A + (size_t)(m0 + srow) * K + scol;
  const unsigned short* gB = Bt + (size_t)(n0 + srow) * K + scol;
  unsigned short* lA = &As[wave * 1024];
  unsigned short* lB = &Bs[wave * 1024];
  f32x4 acc[4][4];
#pragma unroll
  for (int mt = 0; mt < 4; ++mt)
#pragma unroll
    for (int nt = 0; nt < 4; ++nt) acc[mt][nt] = (f32x4){0.f, 0.f, 0.f, 0.f};

  for (int k0 = 0; k0 < K; k0 += 32) {
    gld16(gA + k0, lA);
    gld16(gA + 16 * K + k0, lA + 512);
    gld16(gB + k0, lB);
    gld16(gB + 16 * K + k0, lB + 512);
    __syncthreads();
    bf16x8 af[4], bfr[4];
#pragma unroll
    for (int t = 0; t < 4; ++t) {
      af[t]  = *(const bf16x8*)&As[(rw + t * 16 + lrow) * 32 + quad * 8];
      bfr[t] = *(const bf16x8*)&Bs[(cw + t * 16 + lrow) * 32 + quad * 8];
    }
#pragma unroll
    for (int mt = 0; mt < 4; ++mt)
#pragma unroll
      for (int nt = 0; nt < 4; ++nt)
        acc[mt][nt] = __builtin_amdgcn_mfma_f32_16x16x32_bf16(
            af[mt], bfr[nt], acc[mt][nt], 0, 0, 0);
    __syncthreads();
  }
#pragma unroll
  for (int nt = 0; nt < 4; ++nt) {
    int n = n0 + cw + nt * 16 + lrow;
    int slice = n >> 10, noff = n & 1023;
    if (noff >= nact) continue;
    const float* bp = (slice == 0) ? b0 : (slice == 1) ? b1 : b2;
    float bias = bp[noff];
    bool do_elu = n < elu_ncut;
#pragma unroll
    for (int mt = 0; mt < 4; ++mt) {
      int mb = m0 + rw + mt * 16 + quad * 4;
#pragma unroll
      for (int r = 0; r < 4; ++r) {
        int m = mb + r;
        float val = acc[mt][nt][r] + bias;
        if (do_elu) val = (val > 0.f) ? val + 1.f : expf(val);
        size_t ci = (size_t)m * ldc + n;
        if (out_bf16) {
          ((unsigned short*)Cv)[ci] = f2bf(val);
        } else {
          float* C = (float*)Cv;
          if (mode == 0) C[ci] = val;
          else {
            float g = gw[m * 4 + expert];
            if (mode == 1) C[ci] = g * val;
            else           C[ci] += g * val;
          }
        }
      }
    }
  }
}

// --------------------------------------------- MFMA flash attention ---------
template <int HD>
__global__ __launch_bounds__(256) void attn_mfma(
    const unsigned short* __restrict__ q, const unsigned short* __restrict__ k,
    const unsigned short* __restrict__ v, const int* __restrict__ amask,
    unsigned short* __restrict__ ao, int ldq, int ldo, int w2) {
  constexpr int HDP = (HD + 31) & ~31;  // 128 or 96
  constexpr int DCH = HDP / 32;         // 4 or 3
  constexpr int NDT = HDP / 16;         // 8 or 6
  constexpr int QT = 64, KT = 32;
  constexpr int KLD = HDP + 8;
  constexpr int VLD = KT + 4;
  __shared__ __align__(16) unsigned short Ks[KT * KLD];
  __shared__ __align__(16) _Float16 Vt[HDP * VLD];
  __shared__ unsigned char am[S_];
  int tid = threadIdx.x, wave = tid >> 6, lane = tid & 63;
  int quad = lane >> 4, l15 = lane & 15;
  int q0 = blockIdx.x * QT, h = blockIdx.y, b = blockIdx.z;
  const float scale = rsqrtf((float)HD);
  size_t baseq = ((size_t)b * S_) * ldq + (size_t)h * HD;
  size_t baseo = ((size_t)b * S_) * ldo + (size_t)h * HD;

  for (int i = tid; i < S_; i += 256) am[i] = (unsigned char)(amask[b * S_ + i] != 0);

  int qrow = q0 + wave * 16 + l15;
  bf16x8 qf[DCH];
#pragma unroll
  for (int c = 0; c < DCH; ++c)
#pragma unroll
    for (int j = 0; j < 8; ++j) {
      int d = c * 32 + quad * 8 + j;
      qf[c][j] = (d < HD) ? (short)q[baseq + (size_t)qrow * ldq + d] : (short)0;
    }

  float m_run = -1e30f, l_run = 0.f;
  f32x4 accd[NDT];
#pragma unroll
  for (int dt = 0; dt < NDT; ++dt) accd[dt] = (f32x4){0.f, 0.f, 0.f, 0.f};

  for (int j0 = 0; j0 < S_; j0 += KT) {
    if (j0 > q0 + QT - 1 + w2) break;
    if (j0 + KT - 1 < q0 - w2) continue;
    __syncthreads();
    for (int idx = tid; idx < KT * HDP; idx += 256) {
      int key = idx / HDP, d = idx % HDP;
      unsigned short kv_ = 0; float vv = 0.f;
      if (d < HD) {
        size_t g = baseq + (size_t)(j0 + key) * ldq + d;
        kv_ = k[g];
        vv = bf2f(v[g]);
      }
      Ks[key * KLD + d] = kv_;
      Vt[d * VLD + key] = (_Float16)vv;
    }
    __syncthreads();
    f32x4 sf[2];
    sf[0] = (f32x4){0.f, 0.f, 0.f, 0.f};
    sf[1] = (f32x4){0.f, 0.f, 0.f, 0.f};
#pragma unroll
    for (int kt = 0; kt < 2; ++kt)
#pragma unroll
      for (int c = 0; c < DCH; ++c) {
        bf16x8 kf = *(const bf16x8*)&Ks[(kt * 16 + l15) * KLD + c * 32 + quad * 8];
        sf[kt] = __builtin_amdgcn_mfma_f32_16x16x32_bf16(kf, qf[c], sf[kt], 0, 0, 0);
      }
    float sval[2][4];
    bool vld[2][4];
    float mx = -1e30f;
#pragma unroll
    for (int kt = 0; kt < 2; ++kt)
#pragma unroll
      for (int r = 0; r < 4; ++r) {
        int key = j0 + kt * 16 + quad * 4 + r;
        int dj = key - qrow;
        bool ok = (dj <= w2) && (dj >= -w2) && am[key];
        float s = ok ? sf[kt][r] * scale : -1e30f;
        sval[kt][r] = s;
        vld[kt][r] = ok;
        mx = fmaxf(mx, s);
      }
    mx = fmaxf(mx, __shfl_xor(mx, 16));
    mx = fmaxf(mx, __shfl_xor(mx, 32));
    float m_new = fmaxf(m_run, mx);
    float psum = 0.f;
    float pv[2][4];
#pragma unroll
    for (int kt = 0; kt < 2; ++kt)
#pragma unroll
      for (int r = 0; r < 4; ++r) {
        float p = vld[kt][r] ? expf(sval[kt][r] - m_new) : 0.f;
        pv[kt][r] = p;
        psum += p;
      }
    psum += __shfl_xor(psum, 16);
    psum += __shfl_xor(psum, 32);
    float alpha = expf(m_run - m_new);
    m_run = m_new;
    l_run = l_run * alpha + psum;
    float aR[4];
#pragma unroll
    for (int r = 0; r < 4; ++r)
      aR[r] = __shfl(alpha, (lane & 48) | (quad * 4 + r));
#pragma unroll
    for (int dt = 0; dt < NDT; ++dt)
#pragma unroll
      for (int r = 0; r < 4; ++r) accd[dt][r] *= aR[r];
    half4 pf0, pf1;
#pragma unroll
    for (int r = 0; r < 4; ++r) { pf0[r] = (_Float16)pv[0][r]; pf1[r] = (_Float16)pv[1][r]; }
#pragma unroll
    for (int dt = 0; dt < NDT; ++dt) {
      half4 vf0 = *(const half4*)&Vt[(dt * 16 + l15) * VLD + quad * 4];
      accd[dt] = __builtin_amdgcn_mfma_f32_16x16x16f16(pf0, vf0, accd[dt], 0, 0, 0);
      half4 vf1 = *(const half4*)&Vt[(dt * 16 + l15) * VLD + 16 + quad * 4];
      accd[dt] = __builtin_amdgcn_mfma_f32_16x16x16f16(pf1, vf1, accd[dt], 0, 0, 0);
    }
  }
  float linv = (l_run > 0.f) ? 1.f / l_run : 0.f;
  float lR[4];
#pragma unroll
  for (int r = 0; r < 4; ++r)
    lR[r] = __shfl(linv, (lane & 48) | (quad * 4 + r));
#pragma unroll
  for (int dt = 0; dt < NDT; ++dt) {
    int d = dt * 16 + l15;
    if (d >= HD) continue;
#pragma unroll
    for (int r = 0; r < 4; ++r) {
      int row = q0 + wave * 16 + quad * 4 + r;
      ao[baseo + (size_t)row * ldo + d] = f2bf(accd[dt][r] * lR[r]);
    }
  }
}

// ------------------------------------------------------ linear attention ----
// Split-K MFMA: kv[bh][d][e] = sum_s K[s][d] V[s][e]. Grid (8 h, 4 b, 8 split),
// each block reduces 128 s-rows via transposed-LDS staging + 16x16x32 MFMA
// (A-frag = Kt rows m=d, B-frag = Vt rows n=e, same pattern as gemm_mfma).
// fp32 partials kvp[split][bh][128][128]; ksum partials from staged Kt.
#define NSPLIT 8
__global__ __launch_bounds__(256) void linkv_mfma(
    const unsigned short* __restrict__ k, const unsigned short* __restrict__ v,
    float* __restrict__ kvp, float* __restrict__ ksump, int ld) {
  constexpr int HD = 128;
  constexpr int TLD = 34;  // shorts; bank step 17, gcd(17,32)=1 -> 2-way only
  __shared__ __align__(16) unsigned short Kt[HD * TLD];
  __shared__ __align__(16) unsigned short Vt[HD * TLD];
  int h = blockIdx.x, b = blockIdx.y, split = blockIdx.z;
  int bh = b * 8 + h;
  int tid = threadIdx.x, wave = tid >> 6, lane = tid & 63;
  int quad = lane >> 4, l15 = lane & 15;
  int rw = (wave >> 1) * 64, cw = (wave & 1) * 64;
  size_t base = ((size_t)b * S_) * ld + (size_t)h * HD;
  int s_begin = split * (S_ / NSPLIT);

  f32x4 acc[4][4];
#pragma unroll
  for (int mt = 0; mt < 4; ++mt)
#pragma unroll
    for (int nt = 0; nt < 4; ++nt) acc[mt][nt] = (f32x4){0.f, 0.f, 0.f, 0.f};
  float ksacc = 0.f;
  int myd = tid & 127, half = tid >> 7;  // ksum: threads 0..127 of halves

  for (int c0 = 0; c0 < S_ / NSPLIT; c0 += 32) {
    // stage transposed: Kt[d][s], Vt[d][s] for s in [c0, c0+32)
    for (int idx = tid; idx < 32 * HD; idx += 256) {
      int d = idx & 127, s = idx >> 7;
      size_t g = base + (size_t)(s_begin + c0 + s) * ld + d;
      Kt[d * TLD + s] = k[g];
      Vt[d * TLD + s] = v[g];
    }
    __syncthreads();
    bf16x8 af[4], bf[4];
#pragma unroll
    for (int t = 0; t < 4; ++t) {
      af[t] = *(const bf16x8*)&Kt[(rw + t * 16 + l15) * TLD + quad * 8];
      bf[t] = *(const bf16x8*)&Vt[(cw + t * 16 + l15) * TLD + quad * 8];
    }
#pragma unroll
    for (int mt = 0; mt < 4; ++mt)
#pragma unroll
      for (int nt = 0; nt < 4; ++nt)
        acc[mt][nt] = __builtin_amdgcn_mfma_f32_16x16x32_bf16(
            af[mt], bf[nt], acc[mt][nt], 0, 0, 0);
    // ksum partial: half 0 sums s 0..15, half 1 sums s 16..31 of row myd
#pragma unroll
    for (int s = 0; s < 16; ++s)
      ksacc += bf2f(Kt[myd * TLD + half * 16 + s]);
    __syncthreads();
  }
  // combine ksum halves via LDS (reuse Kt as float scratch)
  float* red = (float*)Kt;
  if (half == 1) red[myd] = ksacc;
  __syncthreads();
  if (half == 0)
    ksump[((size_t)split * 32 + bh) * HD + myd] = ksacc + red[myd];
  // write kv partial: D[row d = rw+mt*16+quad*4+r][col e = cw+nt*16+l15]
  float* kvo = kvp + ((size_t)split * 32 + bh) * (HD * HD);
#pragma unroll
  for (int mt = 0; mt < 4; ++mt)
#pragma unroll
    for (int nt = 0; nt < 4; ++nt) {
      int e = cw + nt * 16 + l15;
#pragma unroll
      for (int r = 0; r < 4; ++r) {
        int d = rw + mt * 16 + quad * 4 + r;
        kvo[(size_t)d * HD + e] = acc[mt][nt][r];
      }
    }
}

// sum the NSPLIT partials -> kv (fp32), ksum (fp32)
__global__ __launch_bounds__(256) void linkv_reduce(
    const float* __restrict__ kvp, const float* __restrict__ ksump,
    float* __restrict__ kv, float* __restrict__ ksum) {
  int idx = blockIdx.x * 256 + threadIdx.x;  // 0 .. 32*128*128-1
  float s = 0.f;
#pragma unroll
  for (int p = 0; p < NSPLIT; ++p) s += kvp[(size_t)p * (32 * 128 * 128) + idx];
  kv[idx] = s;
  if (idx < 32 * 128) {
    float t = 0.f;
#pragma unroll
    for (int p = 0; p < NSPLIT; ++p) t += ksump[(size_t)p * (32 * 128) + idx];
    ksum[idx] = t;
  }
}

__global__ __launch_bounds__(256) void linattn_kernel(
    const unsigned short* __restrict__ q, const float* __restrict__ kv,
    const float* __restrict__ ksum, unsigned short* __restrict__ ao,
    int ldq, int ldo) {
  constexpr int HD = 128;
  int q0 = blockIdx.x * 32;
  int h = blockIdx.y, b = blockIdx.z;
  int tid = threadIdx.x;
  __shared__ float Qs[32][HD + 1];
  __shared__ float den[32];
  size_t baseq = ((size_t)b * S_) * ldq + (size_t)h * HD;
  size_t baseo = ((size_t)b * S_) * ldo + (size_t)h * HD;
  for (int idx = tid; idx < 32 * HD; idx += 256) {
    int r = idx / HD, d = idx % HD;
    Qs[r][d] = bf2f(q[baseq + (size_t)(q0 + r) * ldq + d]);
  }
  __syncthreads();
  int r = tid % 32, grp = tid / 32;
  const float* kvb = kv + (size_t)(b * 8 + h) * HD * HD;
  float acc[16];
#pragma unroll
  for (int c = 0; c < 16; ++c) acc[c] = 0.f;
  for (int d = 0; d < HD; ++d) {
    float qv = Qs[r][d];
    const float* kvr = kvb + (size_t)d * HD + grp * 16;
#pragma unroll
    for (int c = 0; c < 16; ++c) acc[c] += qv * kvr[c];
  }
  if (tid < 32) {
    const float* ks = ksum + (size_t)(b * 8 + h) * HD;
    float dsum = 0.f;
    for (int d = 0; d < HD; ++d) dsum += Qs[tid][d] * ks[d];
    den[tid] = dsum + 1e-6f;
  }
  __syncthreads();
  float inv = 1.f / den[r];
#pragma unroll
  for (int c = 0; c < 16; ++c)
    ao[baseo + (size_t)(q0 + r) * ldo + grp * 16 + c] = f2bf(acc[c] * inv);
}

// ---------------------------------------------------------------- launch ----
extern "C" void kernel_launch(void* const* d_in, const int* in_sizes, int n_in,
                              void* d_out, int out_size, void* d_ws, size_t ws_size,
                              hipStream_t stream) {
  const float* x = (const float*)d_in[0];
  const float* Wg = (const float*)d_in[1];
  const int* amask = (const int*)d_in[34];
  float* out = (float*)d_out;
  char* ws = (char*)d_ws;
  float* gw            = (float*)(ws + 0);                     // 64 KB
  float* kv            = (float*)(ws + (1ull << 20));          // 2 MB
  float* ksum          = (float*)(ws + (3ull << 20) + (1ull << 19));
  unsigned short* xb   = (unsigned short*)(ws + (4ull << 20)); // 8 MB
  unsigned short* qkvT = (unsigned short*)(ws + (12ull << 20));// 6 MB
  unsigned short* woT  = (unsigned short*)(ws + (18ull << 20));// 2 MB
  unsigned short* qkv  = (unsigned short*)(ws + (20ull << 20));// 24 MB [4096][3072]
  unsigned short* aob  = (unsigned short*)(ws + (44ull << 20));// 8 MB [4096][1024]
  float* kvp           = (float*)(ws + (52ull << 20));         // 16 MB partials
  float* ksump         = (float*)(ws + (68ull << 20));         // 128 KB

  conv_kernel<<<16384, 256, 0, stream>>>(x, xb, 1024, 1024);
  gate_kernel<<<4096, 64, 0, stream>>>(x, Wg, gw);

  const int nhs[4] = {8, 12, 8, 8};
  for (int e = 0; e < 4; ++e) {
    const float* Wq = (const float*)d_in[2 + 8 * e + 0];
    const float* bq = (const float*)d_in[2 + 8 * e + 1];
    const float* Wk = (const float*)d_in[2 + 8 * e + 2];
    const float* bk = (const float*)d_in[2 + 8 * e + 3];
    const float* Wv = (const float*)d_in[2 + 8 * e + 4];
    const float* bv = (const float*)d_in[2 + 8 * e + 5];
    const float* Wo = (const float*)d_in[2 + 8 * e + 6];
    const float* bo = (const float*)d_in[2 + 8 * e + 7];
    int nh = nhs[e];
    int hd = H_ / nh;   // 128 or 85
    int pd = nh * hd;   // 1024 or 1020

    wtrans_kernel<<<dim3(32, 32), 256, 0, stream>>>(Wq, qkvT,             1024, pd, pd);
    wtrans_kernel<<<dim3(32, 32), 256, 0, stream>>>(Wk, qkvT + (1 << 20), 1024, pd, pd);
    wtrans_kernel<<<dim3(32, 32), 256, 0, stream>>>(Wv, qkvT + (2 << 20), 1024, pd, pd);
    wtrans_kernel<<<dim3(32, 32), 256, 0, stream>>>(Wo, woT,              pd, 1024, 1024);

    gemm_mfma<<<dim3(24, 32), 256, 0, stream>>>(
        xb, qkvT, bq, bk, bv, qkv, 3072,
        (pd == 1020) ? 1020 : 1024, (e == 2) ? 2048 : 0, 1, 0, nullptr, 0);

    const unsigned short* qb = qkv;
    const unsigned short* kb = qkv + 1024;
    const unsigned short* vb = qkv + 2048;
    if (e == 2) {
      linkv_mfma<<<dim3(8, B_, NSPLIT), 256, 0, stream>>>(kb, vb, kvp, ksump, 3072);
      linkv_reduce<<<(32 * 128 * 128) / 256, 256, 0, stream>>>(kvp, ksump, kv, ksum);
      linattn_kernel<<<dim3(S_ / 32, 8, B_), 256, 0, stream>>>(qb, kv, ksum, aob, 3072, 1024);
    } else {
      int w2 = (e == 3) ? 32 : (1 << 20);
      dim3 agrid(S_ / 64, nh, B_);
      if (hd == 128)
        attn_mfma<128><<<agrid, 256, 0, stream>>>(qb, kb, vb, amask, aob, 3072, 1024, w2);
      else
        attn_mfma<85><<<agrid, 256, 0, stream>>>(qb, kb, vb, amask, aob, 3072, 1024, w2);
    }
    if (pd == 1020)
      zpad_kernel<<<64, 256, 0, stream>>>(aob, 1020);

    gemm_mfma<<<dim3(8, 32), 256, 0, stream>>>(
        aob, woT, bo, bo, bo, out, 1024, 1024, 0, 0, (e == 0) ? 1 : 2, gw, e);
  }
}

// Round 5
// 846.513 us; speedup vs baseline: 7.8068x; 1.1925x over previous
//
#include <hip/hip_runtime.h>
#include <cmath>

#define B_ 4
#define S_ 1024
#define H_ 1024

typedef short bf16x8 __attribute__((ext_vector_type(8)));
typedef float f32x4 __attribute__((ext_vector_type(4)));
typedef _Float16 half4 __attribute__((ext_vector_type(4)));

__device__ __forceinline__ unsigned short f2bf(float f) {
  unsigned u = __float_as_uint(f);
  u += 0x7fff + ((u >> 16) & 1);  // RTNE
  return (unsigned short)(u >> 16);
}
__device__ __forceinline__ float bf2f(unsigned short h) {
  return __uint_as_float(((unsigned)h) << 16);
}
__device__ __forceinline__ void gld16(const void* g, void* l) {
  __builtin_amdgcn_global_load_lds(
      (const __attribute__((address_space(1))) unsigned int*)g,
      (__attribute__((address_space(3))) unsigned int*)l, 16, 0, 0);
}

// ---------------------------------------------------------------- gating ----
__global__ __launch_bounds__(64) void gate_kernel(
    const float* __restrict__ x, const float* __restrict__ Wg,
    float* __restrict__ gw) {
  int t = blockIdx.x;
  int lane = threadIdx.x;
  const float* xr = x + (size_t)t * H_;
  float a0 = 0.f, a1 = 0.f, a2 = 0.f, a3 = 0.f;
  for (int h = lane; h < H_; h += 64) {
    float xv = xr[h];
    const float* wr = Wg + h * 4;
    a0 += xv * wr[0]; a1 += xv * wr[1]; a2 += xv * wr[2]; a3 += xv * wr[3];
  }
  for (int off = 32; off > 0; off >>= 1) {
    a0 += __shfl_down(a0, off);
    a1 += __shfl_down(a1, off);
    a2 += __shfl_down(a2, off);
    a3 += __shfl_down(a3, off);
  }
  if (lane == 0) {
    float v[4] = {a0, a1, a2, a3};
    int i0 = 0; float b0 = v[0];
    for (int e = 1; e < 4; ++e) if (v[e] > b0) { b0 = v[e]; i0 = e; }
    int i1 = -1; float b1 = -INFINITY;
    for (int e = 0; e < 4; ++e) { if (e == i0) continue; if (v[e] > b1) { b1 = v[e]; i1 = e; } }
    float e1v = expf(b1 - b0);
    float w0 = 1.f / (1.f + e1v);
    float w1 = e1v / (1.f + e1v);
    float o[4] = {0.f, 0.f, 0.f, 0.f};
    o[i0] = w0; o[i1] = w1;
    float* g = gw + t * 4;
    g[0] = o[0]; g[1] = o[1]; g[2] = o[2]; g[3] = o[3];
  }
}

// -------------------------------------------------------- fp32 -> bf16 ------
__global__ __launch_bounds__(256) void conv_kernel(
    const float* __restrict__ src, unsigned short* __restrict__ dst,
    int nsrc, int ldsrc) {
  int idx = blockIdx.x * 256 + threadIdx.x;
  int m = idx >> 10, c = idx & 1023;
  dst[idx] = (c < nsrc) ? f2bf(src[(size_t)m * ldsrc + c]) : (unsigned short)0;
}

// zero bf16 cols [c0,1024) of dst[4096][1024]
__global__ __launch_bounds__(256) void zpad_kernel(unsigned short* dst, int c0) {
  int w = 1024 - c0;
  int idx = blockIdx.x * 256 + threadIdx.x;
  int m = idx / w, c = idx % w;
  if (m < 4096) dst[(size_t)m * 1024 + c0 + c] = 0;
}

// --------------------------------------- weight transpose + bf16 (padded) ---
__global__ __launch_bounds__(256) void wtrans_kernel(
    const float* __restrict__ src, unsigned short* __restrict__ dst,
    int ksrc, int nsrc, int ldsrc) {
  __shared__ float tile[32][33];
  int k0 = blockIdx.x * 32, n0 = blockIdx.y * 32;
  int tx = threadIdx.x & 31, ty = threadIdx.x >> 5;
  for (int i = 0; i < 32; i += 8) {
    int k = k0 + ty + i, n = n0 + tx;
    tile[ty + i][tx] = (k < ksrc && n < nsrc) ? src[(size_t)k * ldsrc + n] : 0.f;
  }
  __syncthreads();
  for (int i = 0; i < 32; i += 8) {
    int n = n0 + ty + i, k = k0 + tx;
    dst[(size_t)n * 1024 + k] = f2bf(tile[tx][ty + i]);
  }
}

// ------------------------------------------------------- bf16 MFMA GEMM -----
// remap: bf16 out col -> slice*1152 + (noff/85)*96 + noff%85 (e1 head-pad).
__global__ __launch_bounds__(256) void gemm_mfma(
    const unsigned short* __restrict__ A, const unsigned short* __restrict__ Bt,
    const float* __restrict__ b0, const float* __restrict__ b1,
    const float* __restrict__ b2, void* __restrict__ Cv, int ldc,
    int nact, int elu_ncut, int out_bf16, int mode,
    const float* __restrict__ gw, int expert, int remap) {
  constexpr int K = 1024;
  __shared__ __align__(16) unsigned short As[128 * 32];
  __shared__ __align__(16) unsigned short Bs[128 * 32];
  int tid = threadIdx.x, wave = tid >> 6, lane = tid & 63;
  int quad = lane >> 4, lrow = lane & 15;
  int rw = (wave >> 1) * 64, cw = (wave & 1) * 64;
  int m0 = blockIdx.y * 128, n0 = blockIdx.x * 128;
  int srow = wave * 32 + (lane >> 2);
  int scol = (lane & 3) * 8;
  const unsigned short* gA = A + (size_t)(m0 + srow) * K + scol;
  const unsigned short* gB = Bt + (size_t)(n0 + srow) * K + scol;
  unsigned short* lA = &As[wave * 1024];
  unsigned short* lB = &Bs[wave * 1024];
  f32x4 acc[4][4];
#pragma unroll
  for (int mt = 0; mt < 4; ++mt)
#pragma unroll
    for (int nt = 0; nt < 4; ++nt) acc[mt][nt] = (f32x4){0.f, 0.f, 0.f, 0.f};

  for (int k0 = 0; k0 < K; k0 += 32) {
    gld16(gA + k0, lA);
    gld16(gA + 16 * K + k0, lA + 512);
    gld16(gB + k0, lB);
    gld16(gB + 16 * K + k0, lB + 512);
    __syncthreads();
    bf16x8 af[4], bfr[4];
#pragma unroll
    for (int t = 0; t < 4; ++t) {
      af[t]  = *(const bf16x8*)&As[(rw + t * 16 + lrow) * 32 + quad * 8];
      bfr[t] = *(const bf16x8*)&Bs[(cw + t * 16 + lrow) * 32 + quad * 8];
    }
#pragma unroll
    for (int mt = 0; mt < 4; ++mt)
#pragma unroll
      for (int nt = 0; nt < 4; ++nt)
        acc[mt][nt] = __builtin_amdgcn_mfma_f32_16x16x32_bf16(
            af[mt], bfr[nt], acc[mt][nt], 0, 0, 0);
    __syncthreads();
  }
#pragma unroll
  for (int nt = 0; nt < 4; ++nt) {
    int n = n0 + cw + nt * 16 + lrow;
    int slice = n >> 10, noff = n & 1023;
    if (noff >= nact) continue;
    const float* bp = (slice == 0) ? b0 : (slice == 1) ? b1 : b2;
    float bias = bp[noff];
    bool do_elu = n < elu_ncut;
    int col = n;
    if (remap) {
      int head = (noff * 12337) >> 20;  // noff/85 for noff<1020
      col = slice * 1152 + head * 96 + (noff - head * 85);
    }
#pragma unroll
    for (int mt = 0; mt < 4; ++mt) {
      int mb = m0 + rw + mt * 16 + quad * 4;
#pragma unroll
      for (int r = 0; r < 4; ++r) {
        int m = mb + r;
        float val = acc[mt][nt][r] + bias;
        if (do_elu) val = (val > 0.f) ? val + 1.f : expf(val);
        size_t ci = (size_t)m * ldc + col;
        if (out_bf16) {
          ((unsigned short*)Cv)[ci] = f2bf(val);
        } else {
          float* C = (float*)Cv;
          if (mode == 0) C[ci] = val;
          else {
            float g = gw[m * 4 + expert];
            if (mode == 1) C[ci] = g * val;
            else           C[ci] += g * val;
          }
        }
      }
    }
  }
}

// --------------------------------------------- MFMA flash attention v2 ------
// 512 thr, QT=128 (one 16-query S^T tile per wave), KT=32. Vectorized
// bf16x8 K/V staging prefetched one tile ahead; V^T fp16 writes are
// bank-conflict-free (key=tid&31 mapping). q/k/v head stride = HDP
// (head-padded layout for HD=85); output compact (ld 1024).
template <int HD>
__global__ __launch_bounds__(512) void attn_mfma2(
    const unsigned short* __restrict__ q, const unsigned short* __restrict__ k,
    const unsigned short* __restrict__ v, const int* __restrict__ amask,
    unsigned short* __restrict__ ao, int ldq, int w2) {
  constexpr int HDP = (HD + 31) & ~31;  // 128 or 96
  constexpr int DCH = HDP / 32;         // 4 or 3
  constexpr int NDT = HDP / 16;         // 8 or 6
  constexpr int NCH = HDP / 8;          // 16 or 12
  constexpr int QT = 128, KT = 32;
  constexpr int KLD = HDP + 8;          // shorts; rows stay 16B-aligned
  constexpr int VLD = KT + 4;           // 36 halves
  __shared__ __align__(16) unsigned short Ks[KT * KLD];
  __shared__ __align__(16) _Float16 Vt[HDP * VLD];
  __shared__ unsigned char am[S_];
  int tid = threadIdx.x, wave = tid >> 6, lane = tid & 63;
  int quad = lane >> 4, l15 = lane & 15;
  int q0 = blockIdx.x * QT, h = blockIdx.y, b = blockIdx.z;
  const float scale = rsqrtf((float)HD);
  size_t baseq = ((size_t)b * S_) * ldq + (size_t)h * HDP;
  size_t baseo = ((size_t)b * S_) * H_ + (size_t)h * HD;

  for (int i = tid; i < S_; i += 512) am[i] = (unsigned char)(amask[b * S_ + i] != 0);

  // Q fragments: lane holds Q[query=l15][d=c*32+quad*8+j]
  int qrow = q0 + wave * 16 + l15;
  bf16x8 qf[DCH];
#pragma unroll
  for (int c = 0; c < DCH; ++c)
#pragma unroll
    for (int j = 0; j < 8; ++j) {
      int d = c * 32 + quad * 8 + j;
      qf[c][j] = (d < HD) ? (short)q[baseq + (size_t)qrow * ldq + d] : (short)0;
    }

  // key-tile range (contiguous window)
  int jlo = 0, jhi = S_;
  if (w2 < S_) {
    jlo = q0 - w2; if (jlo < 0) jlo = 0; jlo &= ~(KT - 1);
    jhi = q0 + QT + w2; if (jhi > S_) jhi = S_;
  }

  // staging: thread owns (key = tid&31, 16B chunk c8 = tid>>5)
  int skey = tid & 31, sc8 = tid >> 5;
  bool sact = sc8 < NCH;
  const unsigned short* kg = k + baseq + (size_t)skey * ldq + sc8 * 8;
  const unsigned short* vg = v + baseq + (size_t)skey * ldq + sc8 * 8;
  bf16x8 kreg = {}, vreg = {};
  if (sact) {
    kreg = *(const bf16x8*)(kg + (size_t)jlo * ldq);
    vreg = *(const bf16x8*)(vg + (size_t)jlo * ldq);
  }

  float m_run = -1e30f, l_run = 0.f;
  f32x4 accd[NDT];
#pragma unroll
  for (int dt = 0; dt < NDT; ++dt) accd[dt] = (f32x4){0.f, 0.f, 0.f, 0.f};

  for (int j0 = jlo; j0 < jhi; j0 += KT) {
    __syncthreads();  // prior tile's LDS reads complete
    if (sact) {
      *(bf16x8*)&Ks[skey * KLD + sc8 * 8] = kreg;
#pragma unroll
      for (int j = 0; j < 8; ++j)
        Vt[(sc8 * 8 + j) * VLD + skey] = (_Float16)bf2f((unsigned short)vreg[j]);
    }
    __syncthreads();
    int jn = j0 + KT;
    if (jn < jhi && sact) {  // prefetch next tile (hidden under compute)
      kreg = *(const bf16x8*)(kg + (size_t)jn * ldq);
      vreg = *(const bf16x8*)(vg + (size_t)jn * ldq);
    }
    // S^T = K @ Q^T : two 16-key tiles
    f32x4 sf[2];
    sf[0] = (f32x4){0.f, 0.f, 0.f, 0.f};
    sf[1] = (f32x4){0.f, 0.f, 0.f, 0.f};
#pragma unroll
    for (int kt = 0; kt < 2; ++kt)
#pragma unroll
      for (int c = 0; c < DCH; ++c) {
        bf16x8 kf = *(const bf16x8*)&Ks[(kt * 16 + l15) * KLD + c * 32 + quad * 8];
        sf[kt] = __builtin_amdgcn_mfma_f32_16x16x32_bf16(kf, qf[c], sf[kt], 0, 0, 0);
      }
    // mask + online softmax (query = l15; key = quad*4+r per kt)
    float sval[2][4];
    bool vld[2][4];
    float mx = -1e30f;
#pragma unroll
    for (int kt = 0; kt < 2; ++kt)
#pragma unroll
      for (int r = 0; r < 4; ++r) {
        int key = j0 + kt * 16 + quad * 4 + r;
        int dj = key - qrow;
        bool ok = (dj <= w2) && (dj >= -w2) && am[key];
        float s = ok ? sf[kt][r] * scale : -1e30f;
        sval[kt][r] = s;
        vld[kt][r] = ok;
        mx = fmaxf(mx, s);
      }
    mx = fmaxf(mx, __shfl_xor(mx, 16));
    mx = fmaxf(mx, __shfl_xor(mx, 32));
    float m_new = fmaxf(m_run, mx);
    float psum = 0.f;
    float pv[2][4];
#pragma unroll
    for (int kt = 0; kt < 2; ++kt)
#pragma unroll
      for (int r = 0; r < 4; ++r) {
        float p = vld[kt][r] ? expf(sval[kt][r] - m_new) : 0.f;
        pv[kt][r] = p;
        psum += p;
      }
    psum += __shfl_xor(psum, 16);
    psum += __shfl_xor(psum, 32);
    float alpha = expf(m_run - m_new);
    m_run = m_new;
    l_run = l_run * alpha + psum;
    float aR[4];
#pragma unroll
    for (int r = 0; r < 4; ++r)
      aR[r] = __shfl(alpha, (lane & 48) | (quad * 4 + r));
#pragma unroll
    for (int dt = 0; dt < NDT; ++dt)
#pragma unroll
      for (int r = 0; r < 4; ++r) accd[dt][r] *= aR[r];
    // P (fp16, A-layout) @ V^T tiles
    half4 pf0, pf1;
#pragma unroll
    for (int r = 0; r < 4; ++r) { pf0[r] = (_Float16)pv[0][r]; pf1[r] = (_Float16)pv[1][r]; }
#pragma unroll
    for (int dt = 0; dt < NDT; ++dt) {
      half4 vf0 = *(const half4*)&Vt[(dt * 16 + l15) * VLD + quad * 4];
      accd[dt] = __builtin_amdgcn_mfma_f32_16x16x16f16(pf0, vf0, accd[dt], 0, 0, 0);
      half4 vf1 = *(const half4*)&Vt[(dt * 16 + l15) * VLD + 16 + quad * 4];
      accd[dt] = __builtin_amdgcn_mfma_f32_16x16x16f16(pf1, vf1, accd[dt], 0, 0, 0);
    }
  }
  // O[row=q0+wave*16+quad*4+r][col=dt*16+l15], compact layout
  float linv = (l_run > 0.f) ? 1.f / l_run : 0.f;
  float lR[4];
#pragma unroll
  for (int r = 0; r < 4; ++r)
    lR[r] = __shfl(linv, (lane & 48) | (quad * 4 + r));
#pragma unroll
  for (int dt = 0; dt < NDT; ++dt) {
    int d = dt * 16 + l15;
    if (d >= HD) continue;
#pragma unroll
    for (int r = 0; r < 4; ++r) {
      int row = q0 + wave * 16 + quad * 4 + r;
      ao[baseo + (size_t)row * H_ + d] = f2bf(accd[dt][r] * lR[r]);
    }
  }
}

// ------------------------------------------------------ linear attention ----
#define NSPLIT 8
__global__ __launch_bounds__(256) void linkv_mfma(
    const unsigned short* __restrict__ k, const unsigned short* __restrict__ v,
    float* __restrict__ kvp, float* __restrict__ ksump, int ld) {
  constexpr int HD = 128;
  constexpr int TLD = 34;
  __shared__ __align__(16) unsigned short Kt[HD * TLD];
  __shared__ __align__(16) unsigned short Vt[HD * TLD];
  int h = blockIdx.x, b = blockIdx.y, split = blockIdx.z;
  int bh = b * 8 + h;
  int tid = threadIdx.x, wave = tid >> 6, lane = tid & 63;
  int quad = lane >> 4, l15 = lane & 15;
  int rw = (wave >> 1) * 64, cw = (wave & 1) * 64;
  size_t base = ((size_t)b * S_) * ld + (size_t)h * HD;
  int s_begin = split * (S_ / NSPLIT);

  f32x4 acc[4][4];
#pragma unroll
  for (int mt = 0; mt < 4; ++mt)
#pragma unroll
    for (int nt = 0; nt < 4; ++nt) acc[mt][nt] = (f32x4){0.f, 0.f, 0.f, 0.f};
  float ksacc = 0.f;
  int myd = tid & 127, half = tid >> 7;

  for (int c0 = 0; c0 < S_ / NSPLIT; c0 += 32) {
    for (int idx = tid; idx < 32 * HD; idx += 256) {
      int d = idx & 127, s = idx >> 7;
      size_t g = base + (size_t)(s_begin + c0 + s) * ld + d;
      Kt[d * TLD + s] = k[g];
      Vt[d * TLD + s] = v[g];
    }
    __syncthreads();
    bf16x8 af[4], bf[4];
#pragma unroll
    for (int t = 0; t < 4; ++t) {
      af[t] = *(const bf16x8*)&Kt[(rw + t * 16 + l15) * TLD + quad * 8];
      bf[t] = *(const bf16x8*)&Vt[(cw + t * 16 + l15) * TLD + quad * 8];
    }
#pragma unroll
    for (int mt = 0; mt < 4; ++mt)
#pragma unroll
      for (int nt = 0; nt < 4; ++nt)
        acc[mt][nt] = __builtin_amdgcn_mfma_f32_16x16x32_bf16(
            af[mt], bf[nt], acc[mt][nt], 0, 0, 0);
#pragma unroll
    for (int s = 0; s < 16; ++s)
      ksacc += bf2f(Kt[myd * TLD + half * 16 + s]);
    __syncthreads();
  }
  float* red = (float*)Kt;
  if (half == 1) red[myd] = ksacc;
  __syncthreads();
  if (half == 0)
    ksump[((size_t)split * 32 + bh) * HD + myd] = ksacc + red[myd];
  float* kvo = kvp + ((size_t)split * 32 + bh) * (HD * HD);
#pragma unroll
  for (int mt = 0; mt < 4; ++mt)
#pragma unroll
    for (int nt = 0; nt < 4; ++nt) {
      int e = cw + nt * 16 + l15;
#pragma unroll
      for (int r = 0; r < 4; ++r) {
        int d = rw + mt * 16 + quad * 4 + r;
        kvo[(size_t)d * HD + e] = acc[mt][nt][r];
      }
    }
}

__global__ __launch_bounds__(256) void linkv_reduce(
    const float* __restrict__ kvp, const float* __restrict__ ksump,
    float* __restrict__ kv, float* __restrict__ ksum) {
  int idx = blockIdx.x * 256 + threadIdx.x;
  float s = 0.f;
#pragma unroll
  for (int p = 0; p < NSPLIT; ++p) s += kvp[(size_t)p * (32 * 128 * 128) + idx];
  kv[idx] = s;
  if (idx < 32 * 128) {
    float t = 0.f;
#pragma unroll
    for (int p = 0; p < NSPLIT; ++p) t += ksump[(size_t)p * (32 * 128) + idx];
    ksum[idx] = t;
  }
}

__global__ __launch_bounds__(256) void linattn_kernel(
    const unsigned short* __restrict__ q, const float* __restrict__ kv,
    const float* __restrict__ ksum, unsigned short* __restrict__ ao,
    int ldq, int ldo) {
  constexpr int HD = 128;
  int q0 = blockIdx.x * 32;
  int h = blockIdx.y, b = blockIdx.z;
  int tid = threadIdx.x;
  __shared__ float Qs[32][HD + 1];
  __shared__ float den[32];
  size_t baseq = ((size_t)b * S_) * ldq + (size_t)h * HD;
  size_t baseo = ((size_t)b * S_) * ldo + (size_t)h * HD;
  for (int idx = tid; idx < 32 * HD; idx += 256) {
    int r = idx / HD, d = idx % HD;
    Qs[r][d] = bf2f(q[baseq + (size_t)(q0 + r) * ldq + d]);
  }
  __syncthreads();
  int r = tid % 32, grp = tid / 32;
  const float* kvb = kv + (size_t)(b * 8 + h) * HD * HD;
  float acc[16];
#pragma unroll
  for (int c = 0; c < 16; ++c) acc[c] = 0.f;
  for (int d = 0; d < HD; ++d) {
    float qv = Qs[r][d];
    const float* kvr = kvb + (size_t)d * HD + grp * 16;
#pragma unroll
    for (int c = 0; c < 16; ++c) acc[c] += qv * kvr[c];
  }
  if (tid < 32) {
    const float* ks = ksum + (size_t)(b * 8 + h) * HD;
    float dsum = 0.f;
    for (int d = 0; d < HD; ++d) dsum += Qs[tid][d] * ks[d];
    den[tid] = dsum + 1e-6f;
  }
  __syncthreads();
  float inv = 1.f / den[r];
#pragma unroll
  for (int c = 0; c < 16; ++c)
    ao[baseo + (size_t)(q0 + r) * ldo + grp * 16 + c] = f2bf(acc[c] * inv);
}

// ---------------------------------------------------------------- launch ----
extern "C" void kernel_launch(void* const* d_in, const int* in_sizes, int n_in,
                              void* d_out, int out_size, void* d_ws, size_t ws_size,
                              hipStream_t stream) {
  const float* x = (const float*)d_in[0];
  const float* Wg = (const float*)d_in[1];
  const int* amask = (const int*)d_in[34];
  float* out = (float*)d_out;
  char* ws = (char*)d_ws;
  float* gw            = (float*)(ws + 0);                     // 64 KB
  float* kv            = (float*)(ws + (1ull << 20));          // 2 MB
  float* ksum          = (float*)(ws + (3ull << 20) + (1ull << 19));
  unsigned short* xb   = (unsigned short*)(ws + (4ull << 20)); // 8 MB
  unsigned short* qkvT = (unsigned short*)(ws + (12ull << 20));// 6 MB
  unsigned short* woT  = (unsigned short*)(ws + (18ull << 20));// 2 MB
  unsigned short* qkv  = (unsigned short*)(ws + (20ull << 20));// 27 MB [4096][<=3456]
  unsigned short* aob  = (unsigned short*)(ws + (49ull << 20));// 8 MB [4096][1024]
  float* kvp           = (float*)(ws + (57ull << 20));         // 16 MB
  float* ksump         = (float*)(ws + (73ull << 20));         // 128 KB

  conv_kernel<<<16384, 256, 0, stream>>>(x, xb, 1024, 1024);
  gate_kernel<<<4096, 64, 0, stream>>>(x, Wg, gw);

  const int nhs[4] = {8, 12, 8, 8};
  for (int e = 0; e < 4; ++e) {
    const float* Wq = (const float*)d_in[2 + 8 * e + 0];
    const float* bq = (const float*)d_in[2 + 8 * e + 1];
    const float* Wk = (const float*)d_in[2 + 8 * e + 2];
    const float* bk = (const float*)d_in[2 + 8 * e + 3];
    const float* Wv = (const float*)d_in[2 + 8 * e + 4];
    const float* bv = (const float*)d_in[2 + 8 * e + 5];
    const float* Wo = (const float*)d_in[2 + 8 * e + 6];
    const float* bo = (const float*)d_in[2 + 8 * e + 7];
    int nh = nhs[e];
    int hd = H_ / nh;   // 128 or 85
    int pd = nh * hd;   // 1024 or 1020
    int ldqkv = (e == 1) ? 3456 : 3072;  // e1: heads padded 85->96

    wtrans_kernel<<<dim3(32, 32), 256, 0, stream>>>(Wq, qkvT,             1024, pd, pd);
    wtrans_kernel<<<dim3(32, 32), 256, 0, stream>>>(Wk, qkvT + (1 << 20), 1024, pd, pd);
    wtrans_kernel<<<dim3(32, 32), 256, 0, stream>>>(Wv, qkvT + (2 << 20), 1024, pd, pd);
    wtrans_kernel<<<dim3(32, 32), 256, 0, stream>>>(Wo, woT,              pd, 1024, 1024);

    gemm_mfma<<<dim3(24, 32), 256, 0, stream>>>(
        xb, qkvT, bq, bk, bv, qkv, ldqkv,
        (pd == 1020) ? 1020 : 1024, (e == 2) ? 2048 : 0, 1, 0, nullptr, 0,
        (e == 1) ? 1 : 0);

    if (e == 2) {
      const unsigned short* qb = qkv;
      const unsigned short* kb = qkv + 1024;
      const unsigned short* vb = qkv + 2048;
      linkv_mfma<<<dim3(8, B_, NSPLIT), 256, 0, stream>>>(kb, vb, kvp, ksump, 3072);
      linkv_reduce<<<(32 * 128 * 128) / 256, 256, 0, stream>>>(kvp, ksump, kv, ksum);
      linattn_kernel<<<dim3(S_ / 32, 8, B_), 256, 0, stream>>>(qb, kv, ksum, aob, 3072, 1024);
    } else if (e == 1) {
      attn_mfma2<85><<<dim3(S_ / 128, 12, B_), 512, 0, stream>>>(
          qkv, qkv + 1152, qkv + 2304, amask, aob, 3456, 1 << 20);
    } else {
      int w2 = (e == 3) ? 32 : (1 << 20);
      attn_mfma2<128><<<dim3(S_ / 128, 8, B_), 512, 0, stream>>>(
          qkv, qkv + 1024, qkv + 2048, amask, aob, 3072, w2);
    }
    if (pd == 1020)
      zpad_kernel<<<64, 256, 0, stream>>>(aob, 1020);

    gemm_mfma<<<dim3(8, 32), 256, 0, stream>>>(
        aob, woT, bo, bo, bo, out, 1024, 1024, 0, 0, (e == 0) ? 1 : 2, gw, e, 0);
  }
}

// Round 6
// 755.897 us; speedup vs baseline: 8.7426x; 1.1199x over previous
//
#include <hip/hip_runtime.h>
#include <cmath>

#define B_ 4
#define S_ 1024
#define H_ 1024

typedef short bf16x8 __attribute__((ext_vector_type(8)));
typedef float f32x4 __attribute__((ext_vector_type(4)));
typedef _Float16 half4 __attribute__((ext_vector_type(4)));

__device__ __forceinline__ unsigned short f2bf(float f) {
  unsigned u = __float_as_uint(f);
  u += 0x7fff + ((u >> 16) & 1);  // RTNE
  return (unsigned short)(u >> 16);
}
__device__ __forceinline__ float bf2f(unsigned short h) {
  return __uint_as_float(((unsigned)h) << 16);
}
__device__ __forceinline__ void gld16(const void* g, void* l) {
  __builtin_amdgcn_global_load_lds(
      (const __attribute__((address_space(1))) unsigned int*)g,
      (__attribute__((address_space(3))) unsigned int*)l, 16, 0, 0);
}

// ---------------------------------------------------------------- gating ----
__global__ __launch_bounds__(64) void gate_kernel(
    const float* __restrict__ x, const float* __restrict__ Wg,
    float* __restrict__ gw) {
  int t = blockIdx.x;
  int lane = threadIdx.x;
  const float* xr = x + (size_t)t * H_;
  float a0 = 0.f, a1 = 0.f, a2 = 0.f, a3 = 0.f;
  for (int h = lane; h < H_; h += 64) {
    float xv = xr[h];
    const float* wr = Wg + h * 4;
    a0 += xv * wr[0]; a1 += xv * wr[1]; a2 += xv * wr[2]; a3 += xv * wr[3];
  }
  for (int off = 32; off > 0; off >>= 1) {
    a0 += __shfl_down(a0, off);
    a1 += __shfl_down(a1, off);
    a2 += __shfl_down(a2, off);
    a3 += __shfl_down(a3, off);
  }
  if (lane == 0) {
    float v[4] = {a0, a1, a2, a3};
    int i0 = 0; float b0 = v[0];
    for (int e = 1; e < 4; ++e) if (v[e] > b0) { b0 = v[e]; i0 = e; }
    int i1 = -1; float b1 = -INFINITY;
    for (int e = 0; e < 4; ++e) { if (e == i0) continue; if (v[e] > b1) { b1 = v[e]; i1 = e; } }
    float e1v = expf(b1 - b0);
    float w0 = 1.f / (1.f + e1v);
    float w1 = e1v / (1.f + e1v);
    float o[4] = {0.f, 0.f, 0.f, 0.f};
    o[i0] = w0; o[i1] = w1;
    float* g = gw + t * 4;
    g[0] = o[0]; g[1] = o[1]; g[2] = o[2]; g[3] = o[3];
  }
}

// -------------------------------------------------------- fp32 -> bf16 ------
__global__ __launch_bounds__(256) void conv_kernel(
    const float* __restrict__ src, unsigned short* __restrict__ dst,
    int nsrc, int ldsrc) {
  int idx = blockIdx.x * 256 + threadIdx.x;
  int m = idx >> 10, c = idx & 1023;
  dst[idx] = (c < nsrc) ? f2bf(src[(size_t)m * ldsrc + c]) : (unsigned short)0;
}

// zero bf16 cols [c0,1024) of dst[4096][1024]
__global__ __launch_bounds__(256) void zpad_kernel(unsigned short* dst, int c0) {
  int w = 1024 - c0;
  int idx = blockIdx.x * 256 + threadIdx.x;
  int m = idx / w, c = idx % w;
  if (m < 4096) dst[(size_t)m * 1024 + c0 + c] = 0;
}

// --------------------- weight transpose + bf16, 4 matrices in one launch ----
// z<3: Wq/Wk/Wv [1024 x pd] -> dst[n][k]; z=3: Wo [pd x 1024] -> dst.
__global__ __launch_bounds__(256) void wtrans4_kernel(
    const float* __restrict__ s0, const float* __restrict__ s1,
    const float* __restrict__ s2, const float* __restrict__ s3,
    unsigned short* __restrict__ d0, unsigned short* __restrict__ d1,
    unsigned short* __restrict__ d2, unsigned short* __restrict__ d3, int pd) {
  __shared__ float tile[32][33];
  int z = blockIdx.z;
  const float* src = (z == 0) ? s0 : (z == 1) ? s1 : (z == 2) ? s2 : s3;
  unsigned short* dst = (z == 0) ? d0 : (z == 1) ? d1 : (z == 2) ? d2 : d3;
  int ksrc = (z < 3) ? 1024 : pd;
  int nsrc = (z < 3) ? pd : 1024;
  int ldsrc = (z < 3) ? pd : 1024;
  int k0 = blockIdx.x * 32, n0 = blockIdx.y * 32;
  int tx = threadIdx.x & 31, ty = threadIdx.x >> 5;
  for (int i = 0; i < 32; i += 8) {
    int k = k0 + ty + i, n = n0 + tx;
    tile[ty + i][tx] = (k < ksrc && n < nsrc) ? src[(size_t)k * ldsrc + n] : 0.f;
  }
  __syncthreads();
  for (int i = 0; i < 32; i += 8) {
    int n = n0 + ty + i, k = k0 + tx;
    dst[(size_t)n * 1024 + k] = f2bf(tile[tx][ty + i]);
  }
}

// ------------------------------------------------------- bf16 MFMA GEMM -----
// remap: bf16 out col -> slice*1152 + (noff/85)*96 + noff%85 (e1 head-pad).
// qscale applied for n < qs_ncut (folds softmax scale*log2e into Q).
__global__ __launch_bounds__(256) void gemm_mfma(
    const unsigned short* __restrict__ A, const unsigned short* __restrict__ Bt,
    const float* __restrict__ b0, const float* __restrict__ b1,
    const float* __restrict__ b2, void* __restrict__ Cv, int ldc,
    int nact, int elu_ncut, int out_bf16, int mode,
    const float* __restrict__ gw, int expert, int remap,
    int qs_ncut, float qscale) {
  constexpr int K = 1024;
  __shared__ __align__(16) unsigned short As[128 * 32];
  __shared__ __align__(16) unsigned short Bs[128 * 32];
  int tid = threadIdx.x, wave = tid >> 6, lane = tid & 63;
  int quad = lane >> 4, lrow = lane & 15;
  int rw = (wave >> 1) * 64, cw = (wave & 1) * 64;
  int m0 = blockIdx.y * 128, n0 = blockIdx.x * 128;
  int srow = wave * 32 + (lane >> 2);
  int scol = (lane & 3) * 8;
  const unsigned short* gA = A + (size_t)(m0 + srow) * K + scol;
  const unsigned short* gB = Bt + (size_t)(n0 + srow) * K + scol;
  unsigned short* lA = &As[wave * 1024];
  unsigned short* lB = &Bs[wave * 1024];
  f32x4 acc[4][4];
#pragma unroll
  for (int mt = 0; mt < 4; ++mt)
#pragma unroll
    for (int nt = 0; nt < 4; ++nt) acc[mt][nt] = (f32x4){0.f, 0.f, 0.f, 0.f};

  for (int k0 = 0; k0 < K; k0 += 32) {
    gld16(gA + k0, lA);
    gld16(gA + 16 * K + k0, lA + 512);
    gld16(gB + k0, lB);
    gld16(gB + 16 * K + k0, lB + 512);
    __syncthreads();
    bf16x8 af[4], bfr[4];
#pragma unroll
    for (int t = 0; t < 4; ++t) {
      af[t]  = *(const bf16x8*)&As[(rw + t * 16 + lrow) * 32 + quad * 8];
      bfr[t] = *(const bf16x8*)&Bs[(cw + t * 16 + lrow) * 32 + quad * 8];
    }
#pragma unroll
    for (int mt = 0; mt < 4; ++mt)
#pragma unroll
      for (int nt = 0; nt < 4; ++nt)
        acc[mt][nt] = __builtin_amdgcn_mfma_f32_16x16x32_bf16(
            af[mt], bfr[nt], acc[mt][nt], 0, 0, 0);
    __syncthreads();
  }
#pragma unroll
  for (int nt = 0; nt < 4; ++nt) {
    int n = n0 + cw + nt * 16 + lrow;
    int slice = n >> 10, noff = n & 1023;
    if (noff >= nact) continue;
    const float* bp = (slice == 0) ? b0 : (slice == 1) ? b1 : b2;
    float bias = bp[noff];
    bool do_elu = n < elu_ncut;
    bool do_qs = n < qs_ncut;
    int col = n;
    if (remap) {
      int head = (noff * 12337) >> 20;  // noff/85 for noff<1020
      col = slice * 1152 + head * 96 + (noff - head * 85);
    }
#pragma unroll
    for (int mt = 0; mt < 4; ++mt) {
      int mb = m0 + rw + mt * 16 + quad * 4;
#pragma unroll
      for (int r = 0; r < 4; ++r) {
        int m = mb + r;
        float val = acc[mt][nt][r] + bias;
        if (do_elu) val = (val > 0.f) ? val + 1.f : expf(val);
        if (do_qs) val *= qscale;
        size_t ci = (size_t)m * ldc + col;
        if (out_bf16) {
          ((unsigned short*)Cv)[ci] = f2bf(val);
        } else {
          float* C = (float*)Cv;
          if (mode == 0) C[ci] = val;
          else {
            float g = gw[m * 4 + expert];
            if (mode == 1) C[ci] = g * val;
            else           C[ci] += g * val;
          }
        }
      }
    }
  }
}

// --------------------------------------------- MFMA flash attention v3 ------
// 512 thr, QT=128, KT=64. Scores pre-scaled into log2 domain (scale*log2e
// folded into Q projection) -> p/alpha are single v_exp_f32 (exp2).
// Attention mask as ballot-built u64 bitmask words (1 broadcast read/tile).
// Transposed-score S^T = K@Q^T, P^T(f16) @ V^T via 16x16x16f16.
template <int HD, bool LOCAL>
__global__ __launch_bounds__(512) void attn_mfma3(
    const unsigned short* __restrict__ q, const unsigned short* __restrict__ k,
    const unsigned short* __restrict__ v, const int* __restrict__ amask,
    unsigned short* __restrict__ ao, int ldq) {
  constexpr int HDP = (HD + 31) & ~31;  // 128 or 96
  constexpr int DCH = HDP / 32;         // 4 or 3
  constexpr int NDT = HDP / 16;         // 8 or 6
  constexpr int NCH = HDP / 8;          // 16 or 12
  constexpr int QT = 128, KT = 64;
  constexpr int KLD = HDP + 8;          // shorts, rows 16B-aligned
  constexpr int VLD = KT + 4;           // 68 halves, rows 8B-aligned
  constexpr int W2 = 32;                // local half-window
  __shared__ __align__(16) unsigned short Ks[KT * KLD];
  __shared__ __align__(16) _Float16 Vt[HDP * VLD];
  __shared__ unsigned long long amq[S_ / 64];
  int tid = threadIdx.x, wave = tid >> 6, lane = tid & 63;
  int quad = lane >> 4, l15 = lane & 15;
  int q0 = blockIdx.x * QT, h = blockIdx.y, b = blockIdx.z;
  size_t baseq = ((size_t)b * S_) * ldq + (size_t)h * HDP;
  size_t baseo = ((size_t)b * S_) * H_ + (size_t)h * HD;

  // mask bits: wave w ballots keys [w*128, w*128+128)
  {
    unsigned long long bb0 = __ballot(amask[b * S_ + wave * 128 + lane] != 0);
    unsigned long long bb1 = __ballot(amask[b * S_ + wave * 128 + 64 + lane] != 0);
    if (lane == 0) { amq[wave * 2] = bb0; amq[wave * 2 + 1] = bb1; }
  }

  // Q fragments (already scaled by rsqrt(hd)*log2e in projection epilogue)
  int qrow = q0 + wave * 16 + l15;
  bf16x8 qf[DCH];
#pragma unroll
  for (int c = 0; c < DCH; ++c)
#pragma unroll
    for (int j = 0; j < 8; ++j) {
      int d = c * 32 + quad * 8 + j;
      qf[c][j] = (d < HD) ? (short)q[baseq + (size_t)qrow * ldq + d] : (short)0;
    }

  int jlo = 0, jhi = S_;
  if (LOCAL) {
    jlo = q0 - W2; if (jlo < 0) jlo = 0; jlo &= ~(KT - 1);
    jhi = q0 + QT + W2; if (jhi > S_) jhi = S_;
  }

  // staging: thread owns chunks c = tid and tid+512; key=c&63, c8=c>>6
  int skey = tid & 63, sc8a = tid >> 6, sc8b = 8 + (tid >> 6);
  bool sactb = sc8b < NCH;
  const unsigned short* kg = k + baseq + (size_t)skey * ldq;
  const unsigned short* vg = v + baseq + (size_t)skey * ldq;
  bf16x8 kra = {}, krb = {}, vra = {}, vrb = {};
  {
    size_t o = (size_t)jlo * ldq;
    kra = *(const bf16x8*)(kg + o + sc8a * 8);
    vra = *(const bf16x8*)(vg + o + sc8a * 8);
    if (sactb) {
      krb = *(const bf16x8*)(kg + o + sc8b * 8);
      vrb = *(const bf16x8*)(vg + o + sc8b * 8);
    }
  }

  float m_run = -1e30f, l_run = 0.f;
  f32x4 accd[NDT];
#pragma unroll
  for (int dt = 0; dt < NDT; ++dt) accd[dt] = (f32x4){0.f, 0.f, 0.f, 0.f};

  for (int j0 = jlo; j0 < jhi; j0 += KT) {
    __syncthreads();  // prior tile's LDS reads done (also covers amq build)
    *(bf16x8*)&Ks[skey * KLD + sc8a * 8] = kra;
#pragma unroll
    for (int j = 0; j < 8; ++j)
      Vt[(sc8a * 8 + j) * VLD + skey] = (_Float16)bf2f((unsigned short)vra[j]);
    if (sactb) {
      *(bf16x8*)&Ks[skey * KLD + sc8b * 8] = krb;
#pragma unroll
      for (int j = 0; j < 8; ++j)
        Vt[(sc8b * 8 + j) * VLD + skey] = (_Float16)bf2f((unsigned short)vrb[j]);
    }
    __syncthreads();
    int jn = j0 + KT;
    if (jn < jhi) {  // prefetch next tile under compute
      size_t o = (size_t)jn * ldq;
      kra = *(const bf16x8*)(kg + o + sc8a * 8);
      vra = *(const bf16x8*)(vg + o + sc8a * 8);
      if (sactb) {
        krb = *(const bf16x8*)(kg + o + sc8b * 8);
        vrb = *(const bf16x8*)(vg + o + sc8b * 8);
      }
    }
    // S^T: four 16-key tiles
    f32x4 sf[4];
#pragma unroll
    for (int kt = 0; kt < 4; ++kt) {
      sf[kt] = (f32x4){0.f, 0.f, 0.f, 0.f};
#pragma unroll
      for (int c = 0; c < DCH; ++c) {
        bf16x8 kf = *(const bf16x8*)&Ks[(kt * 16 + l15) * KLD + c * 32 + quad * 8];
        sf[kt] = __builtin_amdgcn_mfma_f32_16x16x32_bf16(kf, qf[c], sf[kt], 0, 0, 0);
      }
    }
    // mask + online softmax (log2 domain; query = l15)
    unsigned long long mb = amq[j0 >> 6];
    unsigned mw[2] = {(unsigned)mb, (unsigned)(mb >> 32)};
    float sval[4][4];
    bool vld[4][4];
    float mx = -1e30f;
#pragma unroll
    for (int kt = 0; kt < 4; ++kt) {
      unsigned word = mw[kt >> 1];
      int sh = (kt & 1) * 16 + quad * 4;
#pragma unroll
      for (int r = 0; r < 4; ++r) {
        bool ok = (word >> (sh + r)) & 1;
        if (LOCAL) {
          int dj = (j0 + kt * 16 + quad * 4 + r) - qrow;
          ok = ok && (dj <= W2) && (dj >= -W2);
        }
        float s = ok ? sf[kt][r] : -1e30f;
        sval[kt][r] = s;
        vld[kt][r] = ok;
        mx = fmaxf(mx, s);
      }
    }
    mx = fmaxf(mx, __shfl_xor(mx, 16));
    mx = fmaxf(mx, __shfl_xor(mx, 32));
    float m_new = fmaxf(m_run, mx);
    float psum = 0.f;
    float pv[4][4];
#pragma unroll
    for (int kt = 0; kt < 4; ++kt)
#pragma unroll
      for (int r = 0; r < 4; ++r) {
        float p = vld[kt][r] ? __builtin_amdgcn_exp2f(sval[kt][r] - m_new) : 0.f;
        pv[kt][r] = p;
        psum += p;
      }
    psum += __shfl_xor(psum, 16);
    psum += __shfl_xor(psum, 32);
    float alpha = __builtin_amdgcn_exp2f(m_run - m_new);
    m_run = m_new;
    l_run = l_run * alpha + psum;
    float aR[4];
#pragma unroll
    for (int r = 0; r < 4; ++r)
      aR[r] = __shfl(alpha, (lane & 48) | (quad * 4 + r));
#pragma unroll
    for (int dt = 0; dt < NDT; ++dt)
#pragma unroll
      for (int r = 0; r < 4; ++r) accd[dt][r] *= aR[r];
    // P (f16, A-layout) @ V^T
    half4 pf[4];
#pragma unroll
    for (int kt = 0; kt < 4; ++kt)
#pragma unroll
      for (int r = 0; r < 4; ++r) pf[kt][r] = (_Float16)pv[kt][r];
#pragma unroll
    for (int dt = 0; dt < NDT; ++dt)
#pragma unroll
      for (int kt = 0; kt < 4; ++kt) {
        half4 vf = *(const half4*)&Vt[(dt * 16 + l15) * VLD + kt * 16 + quad * 4];
        accd[dt] = __builtin_amdgcn_mfma_f32_16x16x16f16(pf[kt], vf, accd[dt], 0, 0, 0);
      }
  }
  // O[row=q0+wave*16+quad*4+r][col=dt*16+l15], compact ld=1024
  float linv = (l_run > 0.f) ? 1.f / l_run : 0.f;
  float lR[4];
#pragma unroll
  for (int r = 0; r < 4; ++r)
    lR[r] = __shfl(linv, (lane & 48) | (quad * 4 + r));
#pragma unroll
  for (int dt = 0; dt < NDT; ++dt) {
    int d = dt * 16 + l15;
    if (d >= HD) continue;
#pragma unroll
    for (int r = 0; r < 4; ++r) {
      int row = q0 + wave * 16 + quad * 4 + r;
      ao[baseo + (size_t)row * H_ + d] = f2bf(accd[dt][r] * lR[r]);
    }
  }
}

// ------------------------------------------------------ linear attention ----
#define NSPLIT 8
__global__ __launch_bounds__(256) void linkv_mfma(
    const unsigned short* __restrict__ k, const unsigned short* __restrict__ v,
    float* __restrict__ kvp, float* __restrict__ ksump, int ld) {
  constexpr int HD = 128;
  constexpr int TLD = 34;
  __shared__ __align__(16) unsigned short Kt[HD * TLD];
  __shared__ __align__(16) unsigned short Vt[HD * TLD];
  int h = blockIdx.x, b = blockIdx.y, split = blockIdx.z;
  int bh = b * 8 + h;
  int tid = threadIdx.x, wave = tid >> 6, lane = tid & 63;
  int quad = lane >> 4, l15 = lane & 15;
  int rw = (wave >> 1) * 64, cw = (wave & 1) * 64;
  size_t base = ((size_t)b * S_) * ld + (size_t)h * HD;
  int s_begin = split * (S_ / NSPLIT);

  f32x4 acc[4][4];
#pragma unroll
  for (int mt = 0; mt < 4; ++mt)
#pragma unroll
    for (int nt = 0; nt < 4; ++nt) acc[mt][nt] = (f32x4){0.f, 0.f, 0.f, 0.f};
  float ksacc = 0.f;
  int myd = tid & 127, half = tid >> 7;

  for (int c0 = 0; c0 < S_ / NSPLIT; c0 += 32) {
    for (int idx = tid; idx < 32 * HD; idx += 256) {
      int d = idx & 127, s = idx >> 7;
      size_t g = base + (size_t)(s_begin + c0 + s) * ld + d;
      Kt[d * TLD + s] = k[g];
      Vt[d * TLD + s] = v[g];
    }
    __syncthreads();
    bf16x8 af[4], bf[4];
#pragma unroll
    for (int t = 0; t < 4; ++t) {
      af[t] = *(const bf16x8*)&Kt[(rw + t * 16 + l15) * TLD + quad * 8];
      bf[t] = *(const bf16x8*)&Vt[(cw + t * 16 + l15) * TLD + quad * 8];
    }
#pragma unroll
    for (int mt = 0; mt < 4; ++mt)
#pragma unroll
      for (int nt = 0; nt < 4; ++nt)
        acc[mt][nt] = __builtin_amdgcn_mfma_f32_16x16x32_bf16(
            af[mt], bf[nt], acc[mt][nt], 0, 0, 0);
#pragma unroll
    for (int s = 0; s < 16; ++s)
      ksacc += bf2f(Kt[myd * TLD + half * 16 + s]);
    __syncthreads();
  }
  float* red = (float*)Kt;
  if (half == 1) red[myd] = ksacc;
  __syncthreads();
  if (half == 0)
    ksump[((size_t)split * 32 + bh) * HD + myd] = ksacc + red[myd];
  float* kvo = kvp + ((size_t)split * 32 + bh) * (HD * HD);
#pragma unroll
  for (int mt = 0; mt < 4; ++mt)
#pragma unroll
    for (int nt = 0; nt < 4; ++nt) {
      int e = cw + nt * 16 + l15;
#pragma unroll
      for (int r = 0; r < 4; ++r) {
        int d = rw + mt * 16 + quad * 4 + r;
        kvo[(size_t)d * HD + e] = acc[mt][nt][r];
      }
    }
}

__global__ __launch_bounds__(256) void linkv_reduce(
    const float* __restrict__ kvp, const float* __restrict__ ksump,
    float* __restrict__ kv, float* __restrict__ ksum) {
  int idx = blockIdx.x * 256 + threadIdx.x;
  float s = 0.f;
#pragma unroll
  for (int p = 0; p < NSPLIT; ++p) s += kvp[(size_t)p * (32 * 128 * 128) + idx];
  kv[idx] = s;
  if (idx < 32 * 128) {
    float t = 0.f;
#pragma unroll
    for (int p = 0; p < NSPLIT; ++p) t += ksump[(size_t)p * (32 * 128) + idx];
    ksum[idx] = t;
  }
}

__global__ __launch_bounds__(256) void linattn_kernel(
    const unsigned short* __restrict__ q, const float* __restrict__ kv,
    const float* __restrict__ ksum, unsigned short* __restrict__ ao,
    int ldq, int ldo) {
  constexpr int HD = 128;
  int q0 = blockIdx.x * 32;
  int h = blockIdx.y, b = blockIdx.z;
  int tid = threadIdx.x;
  __shared__ float Qs[32][HD + 1];
  __shared__ float den[32];
  size_t baseq = ((size_t)b * S_) * ldq + (size_t)h * HD;
  size_t baseo = ((size_t)b * S_) * ldo + (size_t)h * HD;
  for (int idx = tid; idx < 32 * HD; idx += 256) {
    int r = idx / HD, d = idx % HD;
    Qs[r][d] = bf2f(q[baseq + (size_t)(q0 + r) * ldq + d]);
  }
  __syncthreads();
  int r = tid % 32, grp = tid / 32;
  const float* kvb = kv + (size_t)(b * 8 + h) * HD * HD;
  float acc[16];
#pragma unroll
  for (int c = 0; c < 16; ++c) acc[c] = 0.f;
  for (int d = 0; d < HD; ++d) {
    float qv = Qs[r][d];
    const float* kvr = kvb + (size_t)d * HD + grp * 16;
#pragma unroll
    for (int c = 0; c < 16; ++c) acc[c] += qv * kvr[c];
  }
  if (tid < 32) {
    const float* ks = ksum + (size_t)(b * 8 + h) * HD;
    float dsum = 0.f;
    for (int d = 0; d < HD; ++d) dsum += Qs[tid][d] * ks[d];
    den[tid] = dsum + 1e-6f;
  }
  __syncthreads();
  float inv = 1.f / den[r];
#pragma unroll
  for (int c = 0; c < 16; ++c)
    ao[baseo + (size_t)(q0 + r) * ldo + grp * 16 + c] = f2bf(acc[c] * inv);
}

// ---------------------------------------------------------------- launch ----
extern "C" void kernel_launch(void* const* d_in, const int* in_sizes, int n_in,
                              void* d_out, int out_size, void* d_ws, size_t ws_size,
                              hipStream_t stream) {
  const float* x = (const float*)d_in[0];
  const float* Wg = (const float*)d_in[1];
  const int* amask = (const int*)d_in[34];
  float* out = (float*)d_out;
  char* ws = (char*)d_ws;
  float* gw            = (float*)(ws + 0);                     // 64 KB
  float* kv            = (float*)(ws + (1ull << 20));          // 2 MB
  float* ksum          = (float*)(ws + (3ull << 20) + (1ull << 19));
  unsigned short* xb   = (unsigned short*)(ws + (4ull << 20)); // 8 MB
  unsigned short* qkvT = (unsigned short*)(ws + (12ull << 20));// 6 MB
  unsigned short* woT  = (unsigned short*)(ws + (18ull << 20));// 2 MB
  unsigned short* qkv  = (unsigned short*)(ws + (20ull << 20));// 27 MB [4096][<=3456]
  unsigned short* aob  = (unsigned short*)(ws + (49ull << 20));// 8 MB [4096][1024]
  float* kvp           = (float*)(ws + (57ull << 20));         // 16 MB
  float* ksump         = (float*)(ws + (73ull << 20));         // 128 KB

  conv_kernel<<<16384, 256, 0, stream>>>(x, xb, 1024, 1024);
  gate_kernel<<<4096, 64, 0, stream>>>(x, Wg, gw);

  const int nhs[4] = {8, 12, 8, 8};
  const float LOG2E = 1.4426950408889634f;
  for (int e = 0; e < 4; ++e) {
    const float* Wq = (const float*)d_in[2 + 8 * e + 0];
    const float* bq = (const float*)d_in[2 + 8 * e + 1];
    const float* Wk = (const float*)d_in[2 + 8 * e + 2];
    const float* bk = (const float*)d_in[2 + 8 * e + 3];
    const float* Wv = (const float*)d_in[2 + 8 * e + 4];
    const float* bv = (const float*)d_in[2 + 8 * e + 5];
    const float* Wo = (const float*)d_in[2 + 8 * e + 6];
    const float* bo = (const float*)d_in[2 + 8 * e + 7];
    int nh = nhs[e];
    int hd = H_ / nh;   // 128 or 85
    int pd = nh * hd;   // 1024 or 1020
    int ldqkv = (e == 1) ? 3456 : 3072;  // e1: heads padded 85->96
    // fold softmax scale (and log2e for exp2 softmax) into Q projection
    int qs_ncut = (e == 2) ? 0 : 1024;
    float qscale = LOG2E / sqrtf((float)hd);

    wtrans4_kernel<<<dim3(32, 32, 4), 256, 0, stream>>>(
        Wq, Wk, Wv, Wo, qkvT, qkvT + (1 << 20), qkvT + (2 << 20), woT, pd);

    gemm_mfma<<<dim3(24, 32), 256, 0, stream>>>(
        xb, qkvT, bq, bk, bv, qkv, ldqkv,
        (pd == 1020) ? 1020 : 1024, (e == 2) ? 2048 : 0, 1, 0, nullptr, 0,
        (e == 1) ? 1 : 0, qs_ncut, qscale);

    if (e == 2) {
      const unsigned short* qb = qkv;
      const unsigned short* kb = qkv + 1024;
      const unsigned short* vb = qkv + 2048;
      linkv_mfma<<<dim3(8, B_, NSPLIT), 256, 0, stream>>>(kb, vb, kvp, ksump, 3072);
      linkv_reduce<<<(32 * 128 * 128) / 256, 256, 0, stream>>>(kvp, ksump, kv, ksum);
      linattn_kernel<<<dim3(S_ / 32, 8, B_), 256, 0, stream>>>(qb, kv, ksum, aob, 3072, 1024);
    } else if (e == 1) {
      attn_mfma3<85, false><<<dim3(S_ / 128, 12, B_), 512, 0, stream>>>(
          qkv, qkv + 1152, qkv + 2304, amask, aob, 3456);
    } else if (e == 3) {
      attn_mfma3<128, true><<<dim3(S_ / 128, 8, B_), 512, 0, stream>>>(
          qkv, qkv + 1024, qkv + 2048, amask, aob, 3072);
    } else {
      attn_mfma3<128, false><<<dim3(S_ / 128, 8, B_), 512, 0, stream>>>(
          qkv, qkv + 1024, qkv + 2048, amask, aob, 3072);
    }
    if (pd == 1020)
      zpad_kernel<<<64, 256, 0, stream>>>(aob, 1020);

    gemm_mfma<<<dim3(8, 32), 256, 0, stream>>>(
        aob, woT, bo, bo, bo, out, 1024, 1024, 0, 0, (e == 0) ? 1 : 2, gw, e, 0,
        0, 1.0f);
  }
}

// Round 7
// 696.363 us; speedup vs baseline: 9.4901x; 1.0855x over previous
//
#include <hip/hip_runtime.h>
#include <cmath>

#define B_ 4
#define S_ 1024
#define H_ 1024

typedef short bf16x8 __attribute__((ext_vector_type(8)));
typedef float f32x4 __attribute__((ext_vector_type(4)));
typedef _Float16 half4 __attribute__((ext_vector_type(4)));

__device__ __forceinline__ unsigned short f2bf(float f) {
  unsigned u = __float_as_uint(f);
  u += 0x7fff + ((u >> 16) & 1);  // RTNE
  return (unsigned short)(u >> 16);
}
__device__ __forceinline__ float bf2f(unsigned short h) {
  return __uint_as_float(((unsigned)h) << 16);
}
__device__ __forceinline__ void gld16(const void* g, void* l) {
  __builtin_amdgcn_global_load_lds(
      (const __attribute__((address_space(1))) unsigned int*)g,
      (__attribute__((address_space(3))) unsigned int*)l, 16, 0, 0);
}

// ---------------------------------------------------------------- gating ----
__global__ __launch_bounds__(64) void gate_kernel(
    const float* __restrict__ x, const float* __restrict__ Wg,
    float* __restrict__ gw) {
  int t = blockIdx.x;
  int lane = threadIdx.x;
  const float* xr = x + (size_t)t * H_;
  float a0 = 0.f, a1 = 0.f, a2 = 0.f, a3 = 0.f;
  for (int h = lane; h < H_; h += 64) {
    float xv = xr[h];
    const float* wr = Wg + h * 4;
    a0 += xv * wr[0]; a1 += xv * wr[1]; a2 += xv * wr[2]; a3 += xv * wr[3];
  }
  for (int off = 32; off > 0; off >>= 1) {
    a0 += __shfl_down(a0, off);
    a1 += __shfl_down(a1, off);
    a2 += __shfl_down(a2, off);
    a3 += __shfl_down(a3, off);
  }
  if (lane == 0) {
    float v[4] = {a0, a1, a2, a3};
    int i0 = 0; float b0 = v[0];
    for (int e = 1; e < 4; ++e) if (v[e] > b0) { b0 = v[e]; i0 = e; }
    int i1 = -1; float b1 = -INFINITY;
    for (int e = 0; e < 4; ++e) { if (e == i0) continue; if (v[e] > b1) { b1 = v[e]; i1 = e; } }
    float e1v = expf(b1 - b0);
    float w0 = 1.f / (1.f + e1v);
    float w1 = e1v / (1.f + e1v);
    float o[4] = {0.f, 0.f, 0.f, 0.f};
    o[i0] = w0; o[i1] = w1;
    float* g = gw + t * 4;
    g[0] = o[0]; g[1] = o[1]; g[2] = o[2]; g[3] = o[3];
  }
}

// -------------------------------------------------------- fp32 -> bf16 ------
__global__ __launch_bounds__(256) void conv_kernel(
    const float* __restrict__ src, unsigned short* __restrict__ dst,
    int nsrc, int ldsrc) {
  int idx = blockIdx.x * 256 + threadIdx.x;
  int m = idx >> 10, c = idx & 1023;
  dst[idx] = (c < nsrc) ? f2bf(src[(size_t)m * ldsrc + c]) : (unsigned short)0;
}

// --------------------- weight transpose + bf16, 4 matrices in one launch ----
// z<3: Wq/Wk/Wv [1024 x pd] -> dst[n][k]; z=3: Wo [pd x 1024] -> dst.
// zero outside source -> stale A-cols at k>=pd are multiplied by 0.
__global__ __launch_bounds__(256) void wtrans4_kernel(
    const float* __restrict__ s0, const float* __restrict__ s1,
    const float* __restrict__ s2, const float* __restrict__ s3,
    unsigned short* __restrict__ d0, unsigned short* __restrict__ d1,
    unsigned short* __restrict__ d2, unsigned short* __restrict__ d3, int pd) {
  __shared__ float tile[32][33];
  int z = blockIdx.z;
  const float* src = (z == 0) ? s0 : (z == 1) ? s1 : (z == 2) ? s2 : s3;
  unsigned short* dst = (z == 0) ? d0 : (z == 1) ? d1 : (z == 2) ? d2 : d3;
  int ksrc = (z < 3) ? 1024 : pd;
  int nsrc = (z < 3) ? pd : 1024;
  int ldsrc = (z < 3) ? pd : 1024;
  int k0 = blockIdx.x * 32, n0 = blockIdx.y * 32;
  int tx = threadIdx.x & 31, ty = threadIdx.x >> 5;
  for (int i = 0; i < 32; i += 8) {
    int k = k0 + ty + i, n = n0 + tx;
    tile[ty + i][tx] = (k < ksrc && n < nsrc) ? src[(size_t)k * ldsrc + n] : 0.f;
  }
  __syncthreads();
  for (int i = 0; i < 32; i += 8) {
    int n = n0 + ty + i, k = k0 + tx;
    dst[(size_t)n * 1024 + k] = f2bf(tile[tx][ty + i]);
  }
}

// ------------------------------------------------------- bf16 MFMA GEMM -----
// remap: bf16 out col -> slice*1152 + (noff/85)*96 + noff%85 (e1 head-pad).
// qscale applied for n < qs_ncut (folds softmax scale*log2e into Q).
__global__ __launch_bounds__(256) void gemm_mfma(
    const unsigned short* __restrict__ A, const unsigned short* __restrict__ Bt,
    const float* __restrict__ b0, const float* __restrict__ b1,
    const float* __restrict__ b2, void* __restrict__ Cv, int ldc,
    int nact, int elu_ncut, int out_bf16, int mode,
    const float* __restrict__ gw, int expert, int remap,
    int qs_ncut, float qscale) {
  constexpr int K = 1024;
  __shared__ __align__(16) unsigned short As[128 * 32];
  __shared__ __align__(16) unsigned short Bs[128 * 32];
  int tid = threadIdx.x, wave = tid >> 6, lane = tid & 63;
  int quad = lane >> 4, lrow = lane & 15;
  int rw = (wave >> 1) * 64, cw = (wave & 1) * 64;
  int m0 = blockIdx.y * 128, n0 = blockIdx.x * 128;
  int srow = wave * 32 + (lane >> 2);
  int scol = (lane & 3) * 8;
  const unsigned short* gA = A + (size_t)(m0 + srow) * K + scol;
  const unsigned short* gB = Bt + (size_t)(n0 + srow) * K + scol;
  unsigned short* lA = &As[wave * 1024];
  unsigned short* lB = &Bs[wave * 1024];
  f32x4 acc[4][4];
#pragma unroll
  for (int mt = 0; mt < 4; ++mt)
#pragma unroll
    for (int nt = 0; nt < 4; ++nt) acc[mt][nt] = (f32x4){0.f, 0.f, 0.f, 0.f};

  for (int k0 = 0; k0 < K; k0 += 32) {
    gld16(gA + k0, lA);
    gld16(gA + 16 * K + k0, lA + 512);
    gld16(gB + k0, lB);
    gld16(gB + 16 * K + k0, lB + 512);
    __syncthreads();
    bf16x8 af[4], bfr[4];
#pragma unroll
    for (int t = 0; t < 4; ++t) {
      af[t]  = *(const bf16x8*)&As[(rw + t * 16 + lrow) * 32 + quad * 8];
      bfr[t] = *(const bf16x8*)&Bs[(cw + t * 16 + lrow) * 32 + quad * 8];
    }
#pragma unroll
    for (int mt = 0; mt < 4; ++mt)
#pragma unroll
      for (int nt = 0; nt < 4; ++nt)
        acc[mt][nt] = __builtin_amdgcn_mfma_f32_16x16x32_bf16(
            af[mt], bfr[nt], acc[mt][nt], 0, 0, 0);
    __syncthreads();
  }
#pragma unroll
  for (int nt = 0; nt < 4; ++nt) {
    int n = n0 + cw + nt * 16 + lrow;
    int slice = n >> 10, noff = n & 1023;
    if (noff >= nact) continue;
    const float* bp = (slice == 0) ? b0 : (slice == 1) ? b1 : b2;
    float bias = bp[noff];
    bool do_elu = n < elu_ncut;
    bool do_qs = n < qs_ncut;
    int col = n;
    if (remap) {
      int head = (noff * 12337) >> 20;  // noff/85 for noff<1020
      col = slice * 1152 + head * 96 + (noff - head * 85);
    }
#pragma unroll
    for (int mt = 0; mt < 4; ++mt) {
      int mb = m0 + rw + mt * 16 + quad * 4;
#pragma unroll
      for (int r = 0; r < 4; ++r) {
        int m = mb + r;
        float val = acc[mt][nt][r] + bias;
        if (do_elu) val = (val > 0.f) ? val + 1.f : expf(val);
        if (do_qs) val *= qscale;
        size_t ci = (size_t)m * ldc + col;
        if (out_bf16) {
          ((unsigned short*)Cv)[ci] = f2bf(val);
        } else {
          float* C = (float*)Cv;
          if (mode == 0) C[ci] = val;
          else {
            float g = gw[m * 4 + expert];
            if (mode == 1) C[ci] = g * val;
            else           C[ci] += g * val;
          }
        }
      }
    }
  }
}

// --------------------------------------------- MFMA flash attention v3 ------
// 512 thr, QT=128, KT=64, log2-domain softmax (scale*log2e folded into Q),
// ballot-built u64 mask words, S^T = K@Q^T, P^T(f16) @ V^T.
template <int HD, bool LOCAL>
__global__ __launch_bounds__(512) void attn_mfma3(
    const unsigned short* __restrict__ q, const unsigned short* __restrict__ k,
    const unsigned short* __restrict__ v, const int* __restrict__ amask,
    unsigned short* __restrict__ ao, int ldq) {
  constexpr int HDP = (HD + 31) & ~31;  // 128 or 96
  constexpr int DCH = HDP / 32;         // 4 or 3
  constexpr int NDT = HDP / 16;         // 8 or 6
  constexpr int NCH = HDP / 8;          // 16 or 12
  constexpr int QT = 128, KT = 64;
  constexpr int KLD = HDP + 8;
  constexpr int VLD = KT + 4;
  constexpr int W2 = 32;
  __shared__ __align__(16) unsigned short Ks[KT * KLD];
  __shared__ __align__(16) _Float16 Vt[HDP * VLD];
  __shared__ unsigned long long amq[S_ / 64];
  int tid = threadIdx.x, wave = tid >> 6, lane = tid & 63;
  int quad = lane >> 4, l15 = lane & 15;
  int q0 = blockIdx.x * QT, h = blockIdx.y, b = blockIdx.z;
  size_t baseq = ((size_t)b * S_) * ldq + (size_t)h * HDP;
  size_t baseo = ((size_t)b * S_) * H_ + (size_t)h * HD;

  {
    unsigned long long bb0 = __ballot(amask[b * S_ + wave * 128 + lane] != 0);
    unsigned long long bb1 = __ballot(amask[b * S_ + wave * 128 + 64 + lane] != 0);
    if (lane == 0) { amq[wave * 2] = bb0; amq[wave * 2 + 1] = bb1; }
  }

  int qrow = q0 + wave * 16 + l15;
  bf16x8 qf[DCH];
#pragma unroll
  for (int c = 0; c < DCH; ++c)
#pragma unroll
    for (int j = 0; j < 8; ++j) {
      int d = c * 32 + quad * 8 + j;
      qf[c][j] = (d < HD) ? (short)q[baseq + (size_t)qrow * ldq + d] : (short)0;
    }

  int jlo = 0, jhi = S_;
  if (LOCAL) {
    jlo = q0 - W2; if (jlo < 0) jlo = 0; jlo &= ~(KT - 1);
    jhi = q0 + QT + W2; if (jhi > S_) jhi = S_;
  }

  int skey = tid & 63, sc8a = tid >> 6, sc8b = 8 + (tid >> 6);
  bool sactb = sc8b < NCH;
  const unsigned short* kg = k + baseq + (size_t)skey * ldq;
  const unsigned short* vg = v + baseq + (size_t)skey * ldq;
  bf16x8 kra = {}, krb = {}, vra = {}, vrb = {};
  {
    size_t o = (size_t)jlo * ldq;
    kra = *(const bf16x8*)(kg + o + sc8a * 8);
    vra = *(const bf16x8*)(vg + o + sc8a * 8);
    if (sactb) {
      krb = *(const bf16x8*)(kg + o + sc8b * 8);
      vrb = *(const bf16x8*)(vg + o + sc8b * 8);
    }
  }

  float m_run = -1e30f, l_run = 0.f;
  f32x4 accd[NDT];
#pragma unroll
  for (int dt = 0; dt < NDT; ++dt) accd[dt] = (f32x4){0.f, 0.f, 0.f, 0.f};

  for (int j0 = jlo; j0 < jhi; j0 += KT) {
    __syncthreads();
    *(bf16x8*)&Ks[skey * KLD + sc8a * 8] = kra;
#pragma unroll
    for (int j = 0; j < 8; ++j)
      Vt[(sc8a * 8 + j) * VLD + skey] = (_Float16)bf2f((unsigned short)vra[j]);
    if (sactb) {
      *(bf16x8*)&Ks[skey * KLD + sc8b * 8] = krb;
#pragma unroll
      for (int j = 0; j < 8; ++j)
        Vt[(sc8b * 8 + j) * VLD + skey] = (_Float16)bf2f((unsigned short)vrb[j]);
    }
    __syncthreads();
    int jn = j0 + KT;
    if (jn < jhi) {
      size_t o = (size_t)jn * ldq;
      kra = *(const bf16x8*)(kg + o + sc8a * 8);
      vra = *(const bf16x8*)(vg + o + sc8a * 8);
      if (sactb) {
        krb = *(const bf16x8*)(kg + o + sc8b * 8);
        vrb = *(const bf16x8*)(vg + o + sc8b * 8);
      }
    }
    f32x4 sf[4];
#pragma unroll
    for (int kt = 0; kt < 4; ++kt) {
      sf[kt] = (f32x4){0.f, 0.f, 0.f, 0.f};
#pragma unroll
      for (int c = 0; c < DCH; ++c) {
        bf16x8 kf = *(const bf16x8*)&Ks[(kt * 16 + l15) * KLD + c * 32 + quad * 8];
        sf[kt] = __builtin_amdgcn_mfma_f32_16x16x32_bf16(kf, qf[c], sf[kt], 0, 0, 0);
      }
    }
    unsigned long long mb = amq[j0 >> 6];
    unsigned mw[2] = {(unsigned)mb, (unsigned)(mb >> 32)};
    float sval[4][4];
    bool vld[4][4];
    float mx = -1e30f;
#pragma unroll
    for (int kt = 0; kt < 4; ++kt) {
      unsigned word = mw[kt >> 1];
      int sh = (kt & 1) * 16 + quad * 4;
#pragma unroll
      for (int r = 0; r < 4; ++r) {
        bool ok = (word >> (sh + r)) & 1;
        if (LOCAL) {
          int dj = (j0 + kt * 16 + quad * 4 + r) - qrow;
          ok = ok && (dj <= W2) && (dj >= -W2);
        }
        float s = ok ? sf[kt][r] : -1e30f;
        sval[kt][r] = s;
        vld[kt][r] = ok;
        mx = fmaxf(mx, s);
      }
    }
    mx = fmaxf(mx, __shfl_xor(mx, 16));
    mx = fmaxf(mx, __shfl_xor(mx, 32));
    float m_new = fmaxf(m_run, mx);
    float psum = 0.f;
    float pv[4][4];
#pragma unroll
    for (int kt = 0; kt < 4; ++kt)
#pragma unroll
      for (int r = 0; r < 4; ++r) {
        float p = vld[kt][r] ? __builtin_amdgcn_exp2f(sval[kt][r] - m_new) : 0.f;
        pv[kt][r] = p;
        psum += p;
      }
    psum += __shfl_xor(psum, 16);
    psum += __shfl_xor(psum, 32);
    float alpha = __builtin_amdgcn_exp2f(m_run - m_new);
    m_run = m_new;
    l_run = l_run * alpha + psum;
    float aR[4];
#pragma unroll
    for (int r = 0; r < 4; ++r)
      aR[r] = __shfl(alpha, (lane & 48) | (quad * 4 + r));
#pragma unroll
    for (int dt = 0; dt < NDT; ++dt)
#pragma unroll
      for (int r = 0; r < 4; ++r) accd[dt][r] *= aR[r];
    half4 pf[4];
#pragma unroll
    for (int kt = 0; kt < 4; ++kt)
#pragma unroll
      for (int r = 0; r < 4; ++r) pf[kt][r] = (_Float16)pv[kt][r];
#pragma unroll
    for (int dt = 0; dt < NDT; ++dt)
#pragma unroll
      for (int kt = 0; kt < 4; ++kt) {
        half4 vf = *(const half4*)&Vt[(dt * 16 + l15) * VLD + kt * 16 + quad * 4];
        accd[dt] = __builtin_amdgcn_mfma_f32_16x16x16f16(pf[kt], vf, accd[dt], 0, 0, 0);
      }
  }
  float linv = (l_run > 0.f) ? 1.f / l_run : 0.f;
  float lR[4];
#pragma unroll
  for (int r = 0; r < 4; ++r)
    lR[r] = __shfl(linv, (lane & 48) | (quad * 4 + r));
#pragma unroll
  for (int dt = 0; dt < NDT; ++dt) {
    int d = dt * 16 + l15;
    if (d >= HD) continue;
#pragma unroll
    for (int r = 0; r < 4; ++r) {
      int row = q0 + wave * 16 + quad * 4 + r;
      ao[baseo + (size_t)row * H_ + d] = f2bf(accd[dt][r] * lR[r]);
    }
  }
}

// ------------------------------------------------------ linear attention ----
// Split-K MFMA producing kv^T partials: D[dv][dk] = sum_s V[s][dv] K[s][dk]
// (A-frag from Vt, B-frag from Kt). ksum partials from staged Kt.
#define NSPLIT 8
__global__ __launch_bounds__(256) void linkv_mfma(
    const unsigned short* __restrict__ k, const unsigned short* __restrict__ v,
    float* __restrict__ kvp, float* __restrict__ ksump, int ld) {
  constexpr int HD = 128;
  constexpr int TLD = 34;
  __shared__ __align__(16) unsigned short Kt[HD * TLD];
  __shared__ __align__(16) unsigned short Vt[HD * TLD];
  int h = blockIdx.x, b = blockIdx.y, split = blockIdx.z;
  int bh = b * 8 + h;
  int tid = threadIdx.x, wave = tid >> 6, lane = tid & 63;
  int quad = lane >> 4, l15 = lane & 15;
  int rw = (wave >> 1) * 64, cw = (wave & 1) * 64;
  size_t base = ((size_t)b * S_) * ld + (size_t)h * HD;
  int s_begin = split * (S_ / NSPLIT);

  f32x4 acc[4][4];
#pragma unroll
  for (int mt = 0; mt < 4; ++mt)
#pragma unroll
    for (int nt = 0; nt < 4; ++nt) acc[mt][nt] = (f32x4){0.f, 0.f, 0.f, 0.f};
  float ksacc = 0.f;
  int myd = tid & 127, half = tid >> 7;

  for (int c0 = 0; c0 < S_ / NSPLIT; c0 += 32) {
    for (int idx = tid; idx < 32 * HD; idx += 256) {
      int d = idx & 127, s = idx >> 7;
      size_t g = base + (size_t)(s_begin + c0 + s) * ld + d;
      Kt[d * TLD + s] = k[g];
      Vt[d * TLD + s] = v[g];
    }
    __syncthreads();
    bf16x8 af[4], bf[4];
#pragma unroll
    for (int t = 0; t < 4; ++t) {
      af[t] = *(const bf16x8*)&Vt[(rw + t * 16 + l15) * TLD + quad * 8];  // A = V^T rows (dv)
      bf[t] = *(const bf16x8*)&Kt[(cw + t * 16 + l15) * TLD + quad * 8];  // B = K^T rows (dk)
    }
#pragma unroll
    for (int mt = 0; mt < 4; ++mt)
#pragma unroll
      for (int nt = 0; nt < 4; ++nt)
        acc[mt][nt] = __builtin_amdgcn_mfma_f32_16x16x32_bf16(
            af[mt], bf[nt], acc[mt][nt], 0, 0, 0);
#pragma unroll
    for (int s = 0; s < 16; ++s)
      ksacc += bf2f(Kt[myd * TLD + half * 16 + s]);
    __syncthreads();
  }
  float* red = (float*)Kt;
  if (half == 1) red[myd] = ksacc;
  __syncthreads();
  if (half == 0)
    ksump[((size_t)split * 32 + bh) * HD + myd] = ksacc + red[myd];
  float* kvo = kvp + ((size_t)split * 32 + bh) * (HD * HD);
#pragma unroll
  for (int mt = 0; mt < 4; ++mt)
#pragma unroll
    for (int nt = 0; nt < 4; ++nt) {
      int dk = cw + nt * 16 + l15;
#pragma unroll
      for (int r = 0; r < 4; ++r) {
        int dv = rw + mt * 16 + quad * 4 + r;
        kvo[(size_t)dv * HD + dk] = acc[mt][nt][r];  // kv^T[dv][dk]
      }
    }
}

// sum partials -> kv^T bf16 [bh][dv][dk], ksum fp32
__global__ __launch_bounds__(256) void linkv_reduce(
    const float* __restrict__ kvp, const float* __restrict__ ksump,
    unsigned short* __restrict__ kvb, float* __restrict__ ksum) {
  int idx = blockIdx.x * 256 + threadIdx.x;
  float s = 0.f;
#pragma unroll
  for (int p = 0; p < NSPLIT; ++p) s += kvp[(size_t)p * (32 * 128 * 128) + idx];
  kvb[idx] = f2bf(s);
  if (idx < 32 * 128) {
    float t = 0.f;
#pragma unroll
    for (int p = 0; p < NSPLIT; ++p) t += ksump[(size_t)p * (32 * 128) + idx];
    ksum[idx] = t;
  }
}

// out[q][e] = (Q[q] @ kv[.,e]) / (Q[q].ksum + 1e-6). Per block: one (b,h),
// 128-query tile; M=N=K=128, 4 waves x 4x4 MFMA; kv^T bf16 in LDS, Q frags
// global->reg; denominator from the same Q regs + ksum(LDS) + quad-reduce.
__global__ __launch_bounds__(256) void linattn_mfma(
    const unsigned short* __restrict__ q, const unsigned short* __restrict__ kvT,
    const float* __restrict__ ksum, unsigned short* __restrict__ ao, int ldq) {
  constexpr int KLD = 136;
  __shared__ __align__(16) unsigned short Ks[128 * KLD];
  __shared__ float ksL[128];
  int tid = threadIdx.x, wave = tid >> 6, lane = tid & 63;
  int quad = lane >> 4, l15 = lane & 15;
  int rw = (wave >> 1) * 64, cw = (wave & 1) * 64;
  int q0 = blockIdx.x * 128, h = blockIdx.y, b = blockIdx.z;
  int bh = b * 8 + h;
  size_t baseq = ((size_t)b * S_) * ldq + (size_t)h * 128;
  size_t baseo = ((size_t)b * S_) * H_ + (size_t)h * 128;
  const unsigned short* kvg = kvT + (size_t)bh * (128 * 128);
  for (int idx = tid; idx < 128 * 16; idx += 256) {
    int e = idx >> 4, c = idx & 15;
    *(bf16x8*)&Ks[e * KLD + c * 8] = *(const bf16x8*)&kvg[e * 128 + c * 8];
  }
  if (tid < 128) ksL[tid] = ksum[(size_t)bh * 128 + tid];
  // Q fragments: qf[mt][kc], lane holds Q[q0+rw+mt*16+l15][kc*32+quad*8+j]
  bf16x8 qf[4][4];
#pragma unroll
  for (int mt = 0; mt < 4; ++mt) {
    const unsigned short* qr = q + baseq + (size_t)(q0 + rw + mt * 16 + l15) * ldq;
#pragma unroll
    for (int kc = 0; kc < 4; ++kc)
      qf[mt][kc] = *(const bf16x8*)&qr[kc * 32 + quad * 8];
  }
  __syncthreads();
  f32x4 acc[4][4];
#pragma unroll
  for (int mt = 0; mt < 4; ++mt)
#pragma unroll
    for (int nt = 0; nt < 4; ++nt) acc[mt][nt] = (f32x4){0.f, 0.f, 0.f, 0.f};
#pragma unroll
  for (int kc = 0; kc < 4; ++kc) {
    bf16x8 bf[4];
#pragma unroll
    for (int nt = 0; nt < 4; ++nt)
      bf[nt] = *(const bf16x8*)&Ks[(cw + nt * 16 + l15) * KLD + kc * 32 + quad * 8];
#pragma unroll
    for (int mt = 0; mt < 4; ++mt)
#pragma unroll
      for (int nt = 0; nt < 4; ++nt)
        acc[mt][nt] = __builtin_amdgcn_mfma_f32_16x16x32_bf16(
            qf[mt][kc], bf[nt], acc[mt][nt], 0, 0, 0);
  }
  // denominator per query row (replicated across quads after xor-reduce)
  float den[4];
#pragma unroll
  for (int mt = 0; mt < 4; ++mt) {
    float s = 0.f;
#pragma unroll
    for (int kc = 0; kc < 4; ++kc)
#pragma unroll
      for (int j = 0; j < 8; ++j)
        s += bf2f((unsigned short)qf[mt][kc][j]) * ksL[kc * 32 + quad * 8 + j];
    s += __shfl_xor(s, 16);
    s += __shfl_xor(s, 32);
    den[mt] = s;
  }
#pragma unroll
  for (int mt = 0; mt < 4; ++mt)
#pragma unroll
    for (int r = 0; r < 4; ++r) {
      float dv = __shfl(den[mt], (lane & 48) | (quad * 4 + r));
      float inv = 1.f / (dv + 1e-6f);
      int row = q0 + rw + mt * 16 + quad * 4 + r;
#pragma unroll
      for (int nt = 0; nt < 4; ++nt) {
        int col = cw + nt * 16 + l15;
        ao[baseo + (size_t)row * H_ + col] = f2bf(acc[mt][nt][r] * inv);
      }
    }
}

// ---------------------------------------------------------------- launch ----
extern "C" void kernel_launch(void* const* d_in, const int* in_sizes, int n_in,
                              void* d_out, int out_size, void* d_ws, size_t ws_size,
                              hipStream_t stream) {
  const float* x = (const float*)d_in[0];
  const float* Wg = (const float*)d_in[1];
  const int* amask = (const int*)d_in[34];
  float* out = (float*)d_out;
  char* ws = (char*)d_ws;
  float* gw            = (float*)(ws + 0);                     // 64 KB
  unsigned short* kvb  = (unsigned short*)(ws + (1ull << 20)); // 512 KB kv^T bf16
  float* ksum          = (float*)(ws + (3ull << 20) + (1ull << 19));
  unsigned short* xb   = (unsigned short*)(ws + (4ull << 20)); // 8 MB
  unsigned short* qkvT = (unsigned short*)(ws + (12ull << 20));// 6 MB
  unsigned short* woT  = (unsigned short*)(ws + (18ull << 20));// 2 MB
  unsigned short* qkv  = (unsigned short*)(ws + (20ull << 20));// 27 MB [4096][<=3456]
  unsigned short* aob  = (unsigned short*)(ws + (49ull << 20));// 8 MB [4096][1024]
  float* kvp           = (float*)(ws + (57ull << 20));         // 16 MB
  float* ksump         = (float*)(ws + (73ull << 20));         // 128 KB

  conv_kernel<<<16384, 256, 0, stream>>>(x, xb, 1024, 1024);
  gate_kernel<<<4096, 64, 0, stream>>>(x, Wg, gw);

  const int nhs[4] = {8, 12, 8, 8};
  const float LOG2E = 1.4426950408889634f;
  for (int e = 0; e < 4; ++e) {
    const float* Wq = (const float*)d_in[2 + 8 * e + 0];
    const float* bq = (const float*)d_in[2 + 8 * e + 1];
    const float* Wk = (const float*)d_in[2 + 8 * e + 2];
    const float* bk = (const float*)d_in[2 + 8 * e + 3];
    const float* Wv = (const float*)d_in[2 + 8 * e + 4];
    const float* bv = (const float*)d_in[2 + 8 * e + 5];
    const float* Wo = (const float*)d_in[2 + 8 * e + 6];
    const float* bo = (const float*)d_in[2 + 8 * e + 7];
    int nh = nhs[e];
    int hd = H_ / nh;   // 128 or 85
    int pd = nh * hd;   // 1024 or 1020
    int ldqkv = (e == 1) ? 3456 : 3072;  // e1: heads padded 85->96
    int qs_ncut = (e == 2) ? 0 : 1024;   // fold scale*log2e into Q (not e2)
    float qscale = LOG2E / sqrtf((float)hd);

    wtrans4_kernel<<<dim3(32, 32, 4), 256, 0, stream>>>(
        Wq, Wk, Wv, Wo, qkvT, qkvT + (1 << 20), qkvT + (2 << 20), woT, pd);

    gemm_mfma<<<dim3(24, 32), 256, 0, stream>>>(
        xb, qkvT, bq, bk, bv, qkv, ldqkv,
        (pd == 1020) ? 1020 : 1024, (e == 2) ? 2048 : 0, 1, 0, nullptr, 0,
        (e == 1) ? 1 : 0, qs_ncut, qscale);

    if (e == 2) {
      const unsigned short* qb = qkv;
      const unsigned short* kb = qkv + 1024;
      const unsigned short* vb = qkv + 2048;
      linkv_mfma<<<dim3(8, B_, NSPLIT), 256, 0, stream>>>(kb, vb, kvp, ksump, 3072);
      linkv_reduce<<<(32 * 128 * 128) / 256, 256, 0, stream>>>(kvp, ksump, kvb, ksum);
      linattn_mfma<<<dim3(S_ / 128, 8, B_), 256, 0, stream>>>(qb, kvb, ksum, aob, 3072);
    } else if (e == 1) {
      attn_mfma3<85, false><<<dim3(S_ / 128, 12, B_), 512, 0, stream>>>(
          qkv, qkv + 1152, qkv + 2304, amask, aob, 3456);
    } else if (e == 3) {
      attn_mfma3<128, true><<<dim3(S_ / 128, 8, B_), 512, 0, stream>>>(
          qkv, qkv + 1024, qkv + 2048, amask, aob, 3072);
    } else {
      attn_mfma3<128, false><<<dim3(S_ / 128, 8, B_), 512, 0, stream>>>(
          qkv, qkv + 1024, qkv + 2048, amask, aob, 3072);
    }
    // no zpad: woT rows k>=pd are zero, stale aob cols are annihilated

    gemm_mfma<<<dim3(8, 32), 256, 0, stream>>>(
        aob, woT, bo, bo, bo, out, 1024, 1024, 0, 0, (e == 0) ? 1 : 2, gw, e, 0,
        0, 1.0f);
  }
}